// Round 5
// baseline (732.432 us; speedup 1.0000x reference)
//
#include <hip/hip_runtime.h>

// SerializedMamba on MI355X (gfx950).
// R16: fix R15's two regressions (FETCH 35->133MB from bad XCD swizzle;
//      4-way LDS conflicts from 2-bit in-row XOR).
//      (a) XCD swizzle REVERTED: linear-chunk-per-XCD made each XCD stream
//          all of A through its private L2 (8x16MB ~= measured 133MB).
//      (b) depth-2 pipeline kept (3 bufs, BK=32, counted vmcnt never 0
//          mid-loop, raw barriers), with a NEW LDS bijection:
//          slot sub = (qc + (row>>1)) & 3  ->  s mod 8 covers all 8 bank
//          classes exactly 2x over 16 fragment rows = 2-way = free (m136).
//          Same mapping on stage source and ds_read (involution, rule #21).
// R13: conv_silu vectorized rolling window; gld_lds width=16 staging.
// R12: scan LC=64/NCH=256, fast-path exp power chain (checkA_k-verified).

#define DEV __device__ __forceinline__

typedef unsigned short u16;
typedef u16    u16x8  __attribute__((ext_vector_type(8)));
typedef __bf16 bf16x8 __attribute__((ext_vector_type(8)));
typedef float  f32x4  __attribute__((ext_vector_type(4)));

static constexpr int L_SEQ = 16384;
static constexpr int LC    = 64;    // scan chunk length
static constexpr int NCH   = 256;   // number of chunks

DEV u16 f2b(float x){
  union { float f; unsigned u; } c; c.f = x;
  unsigned u = c.u;
  return (u16)((u + 0x7fffu + ((u >> 16) & 1u)) >> 16);   // RNE
}
DEV float b2f(u16 h){
  union { unsigned u; float f; } c; c.u = ((unsigned)h) << 16;
  return c.f;
}
DEV int ldix(const void* p, int l, bool is64){
  return is64 ? (int)((const long long*)p)[l] : ((const int*)p)[l];
}
DEV float siluf(float x){ return x / (1.f + __expf(-x)); }
DEV float softplusf(float x){ return x > 20.f ? x : log1pf(__expf(x)); }
DEV float geluf(float x){ return 0.5f * x * (1.f + erff(x * 0.70710678118f)); }

// direct global->LDS async copy, 16B per lane (dest must be wave-uniform
// base + lane*16 -- holds for linear tid*16 layouts)
DEV void gld_lds16(const u16* g, u16* l){
  __builtin_amdgcn_global_load_lds(
      (const __attribute__((address_space(1))) unsigned*)g,
      (__attribute__((address_space(3))) unsigned*)l, 16, 0, 0);
}

// r^(s+1) for s=0..15 via log-depth power chain (15 muls after r2/r4/r8)
DEV void pow16(float r, float* a){
  float r2 = r * r, r4 = r2 * r2, r8 = r4 * r4;
  a[0] = r;        a[1] = r2;       a[2] = r2 * r;    a[3] = r4;
  a[4] = r4 * r;   a[5] = r4 * r2;  a[6] = r4 * a[2]; a[7] = r8;
  a[8] = r8 * r;   a[9] = r8 * r2;  a[10] = r8 * a[2]; a[11] = r8 * r4;
  a[12] = r8 * a[4]; a[13] = r8 * a[5]; a[14] = r8 * a[6]; a[15] = r8 * r8;
}

// ---------------------------------------------------------------------------
__global__ __launch_bounds__(256) void fill_k(float* out, float v, unsigned n){
  unsigned i = blockIdx.x * 256 + threadIdx.x;
  if (i < n) out[i] = v;
}

// flag[0]: index inputs are int64. flag[1]: A-structure mismatch (checkA_k).
__global__ void detect_k(const int* ord32, int* flag){
  flag[0] = (ord32[1] == 0 && ord32[3] == 0 && ord32[5] == 0) ? 1 : 0;
  flag[1] = 0;
}

// verify A_log[d][s] == A_log[d][0] + log(s+1)  (=> A[s] = A[0]*(s+1))
__global__ __launch_bounds__(256) void checkA_k(const float* __restrict__ alog,
                                                int* flag){
  int i = blockIdx.x * 256 + threadIdx.x;   // 16384 = d*16+s
  int s = i & 15;
  float v = alog[i];
  float base = alog[i - s];
  if (fabsf(v - (base + __logf((float)(s + 1)))) > 1e-4f) atomicOr(flag + 1, 1);
}

// fp32 -> bf16 pack of the 4 B^T-layout GEMM weights (dense at ws offset 0)
struct NT4 { const float* src[4]; unsigned off[5]; };
__global__ __launch_bounds__(256) void normw_k(NT4 t, u16* dst){
  unsigned i = blockIdx.x * 256 + threadIdx.x;
  if (i >= t.off[4]) return;
  int s = 0;
  #pragma unroll
  for (int k = 1; k <= 3; k++) s += (i >= t.off[k]) ? 1 : 0;
  dst[i] = f2b(t.src[s][i - t.off[s]]);
}

// transpose-convert: out[n*K + k] = f2b(in[k*N + n])
__global__ __launch_bounds__(256) void convT_kernel(const float* __restrict__ in,
                                                    u16* __restrict__ out, int K, int N){
  __shared__ float t[32][33];
  int k0 = blockIdx.x * 32, n0 = blockIdx.y * 32;
  int tx = threadIdx.x & 31, ty = threadIdx.x >> 5;
  #pragma unroll
  for (int i = 0; i < 32; i += 8)
    t[ty + i][tx] = in[(size_t)(k0 + ty + i) * N + n0 + tx];
  __syncthreads();
  #pragma unroll
  for (int i = 0; i < 32; i += 8)
    out[(size_t)(n0 + ty + i) * K + k0 + tx] = f2b(t[tx][ty + i]);
}

// ---------------------------------------------------------------------------
// layernorms (C=512, one block/row, LDS tree)
// ---------------------------------------------------------------------------
__global__ __launch_bounds__(256) void gather_ln1(const float* __restrict__ feat,
    const void* order, const float* __restrict__ w, const float* __restrict__ b,
    const int* flag, u16* __restrict__ x1b){
  __shared__ float rs_[256], rq_[256];
  const bool is64 = flag[0] != 0;
  int l = blockIdx.x, tid = threadIdx.x;
  int src = ldix(order, l, is64);
  float v0 = feat[(size_t)src * 512 + tid];
  float v1 = feat[(size_t)src * 512 + tid + 256];
  rs_[tid] = v0 + v1; rq_[tid] = v0 * v0 + v1 * v1;
  __syncthreads();
  for (int o = 128; o; o >>= 1){
    if (tid < o){ rs_[tid] += rs_[tid + o]; rq_[tid] += rq_[tid + o]; }
    __syncthreads();
  }
  float mu = rs_[0] * (1.f / 512.f);
  float var = rq_[0] * (1.f / 512.f) - mu * mu;
  float rstd = rsqrtf(var + 1e-5f);
  x1b[(size_t)l * 512 + tid]       = f2b((v0 - mu) * rstd * w[tid]       + b[tid]);
  x1b[(size_t)l * 512 + tid + 256] = f2b((v1 - mu) * rstd * w[tid + 256] + b[tid + 256]);
}

__global__ __launch_bounds__(256) void ln2_kernel(const float* __restrict__ x,
    const float* __restrict__ w, const float* __restrict__ b, u16* __restrict__ h2b){
  __shared__ float rs_[256], rq_[256];
  int l = blockIdx.x, tid = threadIdx.x;
  float v0 = x[(size_t)l * 512 + tid];
  float v1 = x[(size_t)l * 512 + tid + 256];
  rs_[tid] = v0 + v1; rq_[tid] = v0 * v0 + v1 * v1;
  __syncthreads();
  for (int o = 128; o; o >>= 1){
    if (tid < o){ rs_[tid] += rs_[tid + o]; rq_[tid] += rq_[tid + o]; }
    __syncthreads();
  }
  float mu = rs_[0] * (1.f / 512.f);
  float var = rq_[0] * (1.f / 512.f) - mu * mu;
  float rstd = rsqrtf(var + 1e-5f);
  h2b[(size_t)l * 512 + tid]       = f2b((v0 - mu) * rstd * w[tid]       + b[tid]);
  h2b[(size_t)l * 512 + tid + 256] = f2b((v1 - mu) * rstd * w[tid + 256] + b[tid + 256]);
}

// ---------------------------------------------------------------------------
// depthwise causal conv (k=4) + silu -- vectorized rolling window.
// ---------------------------------------------------------------------------
__global__ __launch_bounds__(256) void conv_silu(const u16* __restrict__ xm,
    const float* __restrict__ cw, const float* __restrict__ cb, u16* __restrict__ xcb){
  constexpr int TT = 8;
  const int tid = threadIdx.x;
  const int d0 = (tid & 127) * 8;
  const int t0 = (blockIdx.x * 2 + (tid >> 7)) * TT;

  float wk[4][8], bias[8];
  #pragma unroll
  for (int j = 0; j < 8; j++) bias[j] = cb[d0 + j];
  #pragma unroll
  for (int j = 0; j < 8; j++){
    f32x4 v = *(const f32x4*)(cw + (d0 + j) * 4);
    wk[0][j] = v[0]; wk[1][j] = v[1]; wk[2][j] = v[2]; wk[3][j] = v[3];
  }

  float win[3][8];
  #pragma unroll
  for (int k = 0; k < 3; k++){
    int tt = t0 - 3 + k;
    if (tt >= 0){
      u16x8 v = *(const u16x8*)(xm + (size_t)tt * 1024 + d0);
      #pragma unroll
      for (int j = 0; j < 8; j++) win[k][j] = b2f(v[j]);
    } else {
      #pragma unroll
      for (int j = 0; j < 8; j++) win[k][j] = 0.f;
    }
  }

  #pragma unroll
  for (int t = 0; t < TT; t++){
    u16x8 v = *(const u16x8*)(xm + (size_t)(t0 + t) * 1024 + d0);
    u16x8 o;
    float cu[8];
    #pragma unroll
    for (int j = 0; j < 8; j++){
      cu[j] = b2f(v[j]);
      float acc = bias[j] + win[0][j] * wk[0][j] + win[1][j] * wk[1][j]
                + win[2][j] * wk[2][j] + cu[j] * wk[3][j];
      o[j] = f2b(siluf(acc));
    }
    *(u16x8*)(xcb + (size_t)(t0 + t) * 1024 + d0) = o;
    #pragma unroll
    for (int j = 0; j < 8; j++){
      win[0][j] = win[1][j]; win[1][j] = win[2][j]; win[2][j] = cu[j];
    }
  }
}

// ---------------------------------------------------------------------------
// bf16 MFMA GEMM, C = A (MxK, lda) * B^T (NxK, ldb), fused epilogues.
// ---------------------------------------------------------------------------
enum { M_BF16 = 0, M_INPROJ = 1, M_DT = 2, M_RES = 3, M_GELU = 4, M_FFN2 = 5 };

template<int MODE>
DEV void gemm_epilogue(float v, int m, int n, int N,
    float* __restrict__ outf, u16* __restrict__ outb, u16* __restrict__ outb2,
    const float* __restrict__ auxf, const float* __restrict__ auxw,
    const void* ordv, bool is64){
  size_t o = (size_t)m * N + n;
  if constexpr (MODE == M_BF16){
    outb[o] = f2b(v);
  } else if constexpr (MODE == M_INPROJ){
    if (n < 1024) outb [(size_t)m * 1024 + n]          = f2b(v);
    else          outb2[(size_t)m * 1024 + (n - 1024)] = f2b(siluf(v));
  } else if constexpr (MODE == M_DT){
    outb[o] = f2b(softplusf(v + auxw[n]));
  } else if constexpr (MODE == M_RES){
    int src = ldix(ordv, m, is64);
    outf[o] = v + auxw[(size_t)src * 512 + n];   // + feat[order[m]]
  } else if constexpr (MODE == M_GELU){
    outb[o] = f2b(geluf(v + auxw[n]));
  } else { // M_FFN2: + bias + residual -> fp32 (serialized order)
    outf[o] = v + auxw[n] + auxf[o];
  }
}

// R16: depth-2 pipelined GEMM. BK=32, 3 LDS buffers, counted vmcnt (never 0
// mid-loop), raw barriers. LDS bijection: row's chunk qc lives at slot
// sub = (qc + (row>>1)) & 3  (2-way bank aliasing = free). Stage source uses
// the inverse cg = (sub - (row>>1)) & 3; read uses the forward map (rule #21).
// Requires K % 32 == 0.
template<int BM, int BN, int WM, int WN, int MODE>
__global__ __launch_bounds__(256) void gemm_p2(
    const u16* __restrict__ A, const u16* __restrict__ B,
    int N, int K, int lda, int ldb,
    float* __restrict__ outf, u16* __restrict__ outb, u16* __restrict__ outb2,
    const float* __restrict__ auxf, const float* __restrict__ auxw,
    const void* ordv, const int* flag){
  constexpr int BK = 32;
  constexpr int MI = WM / 16, NI = WN / 16;
  constexpr int WCOLS = BN / WN;
  constexpr int NA = BM * BK / (256 * 8);
  constexpr int NB = BN * BK / (256 * 8);
  constexpr int LPS = NA + NB;               // gld_lds per thread per stage
  static_assert(LPS == 2 || LPS == 4, "vmcnt literals assume LPS in {2,4}");
  __shared__ __align__(16) u16 sA[3][BM * BK];
  __shared__ __align__(16) u16 sB[3][BN * BK];
  const int tid  = threadIdx.x;
  const int wave = tid >> 6, lane = tid & 63;
  const int wr = wave / WCOLS, wc = wave % WCOLS;
  const int m0 = blockIdx.x * BM, n0 = blockIdx.y * BN;   // natural dispatch
  const int rr = lane & 15;          // fragment row within 16
  const int qc = lane >> 4;          // k-chunk 0..3

  f32x4 acc[MI][NI] = {};

  auto stage = [&](int buf, int k0){
    #pragma unroll
    for (int i = 0; i < NA; i++){
      int idx = tid + i * 256;
      int row = idx >> 2, sub = idx & 3;
      int cg = (sub - (row >> 1)) & 3;
      gld_lds16(A + (size_t)(m0 + row) * lda + k0 + cg * 8, &sA[buf][idx * 8]);
    }
    #pragma unroll
    for (int i = 0; i < NB; i++){
      int idx = tid + i * 256;
      int row = idx >> 2, sub = idx & 3;
      int cg = (sub - (row >> 1)) & 3;
      gld_lds16(B + (size_t)(n0 + row) * ldb + k0 + cg * 8, &sB[buf][idx * 8]);
    }
  };

  const int nst = K / BK;
  stage(0, 0);
  if (nst > 1) stage(1, BK);
  for (int st = 0; st < nst; st++){
    if (st + 2 < nst) stage((st + 2) % 3, (st + 2) * BK);
    // wait for MY stage(st): newer stages in flight = nf, each LPS loads
    const int nf = (st + 2 < nst) ? 2 : ((st + 1 < nst) ? 1 : 0);
    if (nf == 2){
      if constexpr (LPS == 4) asm volatile("s_waitcnt vmcnt(8)" ::: "memory");
      else                    asm volatile("s_waitcnt vmcnt(4)" ::: "memory");
    } else if (nf == 1){
      if constexpr (LPS == 4) asm volatile("s_waitcnt vmcnt(4)" ::: "memory");
      else                    asm volatile("s_waitcnt vmcnt(2)" ::: "memory");
    } else {
      asm volatile("s_waitcnt vmcnt(0)" ::: "memory");
    }
    __builtin_amdgcn_s_barrier();        // everyone's stage(st) landed
    __builtin_amdgcn_sched_barrier(0);

    const int cur = st % 3;
    bf16x8 af[MI], bfr[NI];
    #pragma unroll
    for (int i = 0; i < MI; i++){
      int R = wr * WM + i * 16 + rr;
      int slot = (qc + (R >> 1)) & 3;
      af[i] = *(const bf16x8*)(&sA[cur][R * BK + slot * 8]);
    }
    #pragma unroll
    for (int j = 0; j < NI; j++){
      int R = wc * WN + j * 16 + rr;
      int slot = (qc + (R >> 1)) & 3;
      bfr[j] = *(const bf16x8*)(&sB[cur][R * BK + slot * 8]);
    }
    #pragma unroll
    for (int i = 0; i < MI; i++)
      #pragma unroll
      for (int j = 0; j < NI; j++)
        acc[i][j] = __builtin_amdgcn_mfma_f32_16x16x32_bf16(af[i], bfr[j], acc[i][j], 0, 0, 0);

    asm volatile("s_waitcnt lgkmcnt(0)" ::: "memory");
    __builtin_amdgcn_s_barrier();        // all reads of buf[cur] done before
    __builtin_amdgcn_sched_barrier(0);   // next iter's stage overwrites it
  }

  const bool is64 = flag ? (flag[0] != 0) : false;
  // D layout: col(N) = lane&15, row(M) = (lane>>4)*4 + r   [m89-verified]
  #pragma unroll
  for (int i = 0; i < MI; i++)
    #pragma unroll
    for (int j = 0; j < NI; j++)
      #pragma unroll
      for (int r = 0; r < 4; r++){
        int m = m0 + wr * WM + i * 16 + ((lane >> 4) << 2) + r;
        int n = n0 + wc * WN + j * 16 + (lane & 15);
        gemm_epilogue<MODE>(acc[i][j][r], m, n, N, outf, outb, outb2,
                            auxf, auxw, ordv, is64);
      }
}

// Legacy BK=32 single-buffer variant (kept for dt_proj, K=32: single step).
template<int BM, int BN, int WM, int WN, int MODE>
__global__ __launch_bounds__(256) void gemm_bt(
    const u16* __restrict__ A, const u16* __restrict__ B,
    int N, int K, int lda, int ldb,
    float* __restrict__ outf, u16* __restrict__ outb, u16* __restrict__ outb2,
    const float* __restrict__ auxf, const float* __restrict__ auxw,
    const void* ordv, const int* flag){
  constexpr int BK = 32;
  constexpr int MI = WM / 16, NI = WN / 16;
  constexpr int WCOLS = BN / WN;
  constexpr int NA = BM * 4 / 256;
  constexpr int NB = BN * 4 / 256;
  __shared__ __align__(16) u16 sA[BM * BK];
  __shared__ __align__(16) u16 sB[BN * BK];
  const int tid  = threadIdx.x;
  const int wave = tid >> 6, lane = tid & 63;
  const int wr = wave / WCOLS, wc = wave % WCOLS;
  const int m0 = blockIdx.x * BM, n0 = blockIdx.y * BN;
  const int rr = lane & 15;
  const int qk = (lane >> 4) * 8;

  f32x4 acc[MI][NI] = {};

  for (int k0 = 0; k0 < K; k0 += BK){
    #pragma unroll
    for (int i = 0; i < NA; i++){
      int idx = tid + i * 256;
      int r = idx >> 2, c = (idx & 3) * 8;
      gld_lds16(A + (size_t)(m0 + r) * lda + k0 + c, sA + (size_t)idx * 8);
    }
    #pragma unroll
    for (int i = 0; i < NB; i++){
      int idx = tid + i * 256;
      int r = idx >> 2, c = (idx & 3) * 8;
      gld_lds16(B + (size_t)(n0 + r) * ldb + k0 + c, sB + (size_t)idx * 8);
    }
    __syncthreads();

    bf16x8 af[MI], bfr[NI];
    #pragma unroll
    for (int i = 0; i < MI; i++)
      af[i] = *(const bf16x8*)(sA + (wr * WM + i * 16 + rr) * BK + qk);
    #pragma unroll
    for (int j = 0; j < NI; j++)
      bfr[j] = *(const bf16x8*)(sB + (wc * WN + j * 16 + rr) * BK + qk);
    #pragma unroll
    for (int i = 0; i < MI; i++)
      #pragma unroll
      for (int j = 0; j < NI; j++)
        acc[i][j] = __builtin_amdgcn_mfma_f32_16x16x32_bf16(af[i], bfr[j], acc[i][j], 0, 0, 0);
    __syncthreads();
  }

  const bool is64 = flag ? (flag[0] != 0) : false;
  #pragma unroll
  for (int i = 0; i < MI; i++)
    #pragma unroll
    for (int j = 0; j < NI; j++)
      #pragma unroll
      for (int r = 0; r < 4; r++){
        int m = m0 + wr * WM + i * 16 + ((lane >> 4) << 2) + r;
        int n = n0 + wc * WN + j * 16 + (lane & 15);
        gemm_epilogue<MODE>(acc[i][j][r], m, n, N, outf, outb, outb2,
                            auxf, auxw, ordv, is64);
      }
}

// ---------------------------------------------------------------------------
// chunked selective scan (fp32 state; chP/chH bf16, layout [chunk][s][d])
// ---------------------------------------------------------------------------
__global__ __launch_bounds__(256) void scan_pass1(const u16* __restrict__ dt,
    const u16* __restrict__ xc, const u16* __restrict__ dbc,
    const float* __restrict__ alog, const int* __restrict__ flag,
    u16* __restrict__ chP, u16* __restrict__ chH){
  __shared__ float sB[LC * 16];
  const int chunk = blockIdx.x;
  const int d = blockIdx.y * 256 + threadIdx.x;
  const int t0 = chunk * LC;
  for (int i = threadIdx.x; i < LC * 16; i += 256){
    int t = i >> 4, s = i & 15;
    sB[i] = b2f(dbc[(size_t)(t0 + t) * 64 + 32 + s]);
  }
  __syncthreads();
  float h[16];
  #pragma unroll
  for (int s = 0; s < 16; s++) h[s] = 0.f;
  float P[16];
  const bool fastA = (flag[1] == 0);
  if (fastA){
    const float a0 = -__expf(alog[(size_t)d * 16]);
    float R = 1.f;
    for (int t = 0; t < LC; t++){
      float dtv = b2f(dt[(size_t)(t0 + t) * 1024 + d]);
      float xv  = b2f(xc[(size_t)(t0 + t) * 1024 + d]);
      float dtx = dtv * xv;
      float r = __expf(dtv * a0);
      R *= r;
      float a_[16];
      pow16(r, a_);
      #pragma unroll
      for (int s = 0; s < 16; s++)
        h[s] = a_[s] * h[s] + dtx * sB[t * 16 + s];
    }
    pow16(R, P);
  } else {
    float A[16];
    #pragma unroll
    for (int s = 0; s < 16; s++){
      A[s] = -__expf(alog[(size_t)d * 16 + s]);
      P[s] = 1.f;
    }
    for (int t = 0; t < LC; t++){
      float dtv = b2f(dt[(size_t)(t0 + t) * 1024 + d]);
      float xv  = b2f(xc[(size_t)(t0 + t) * 1024 + d]);
      float dtx = dtv * xv;
      #pragma unroll
      for (int s = 0; s < 16; s++){
        float a = __expf(dtv * A[s]);
        P[s] *= a;
        h[s] = a * h[s] + dtx * sB[t * 16 + s];
      }
    }
  }
  #pragma unroll
  for (int s = 0; s < 16; s++){
    chP[((size_t)chunk * 16 + s) * 1024 + d] = f2b(P[s]);   // coalesced over d
    chH[((size_t)chunk * 16 + s) * 1024 + d] = f2b(h[s]);
  }
}

// hin may alias chP: window loads 8 ahead into regs before storing.
__global__ __launch_bounds__(64) void carry_scan(const u16* chP, const u16* chH,
                                                 u16* hin){
  int id = blockIdx.x * 64 + threadIdx.x;   // id = s*1024 + d
  float h = 0.f;
  for (int k = 0; k < NCH; k += 8){
    float P[8], E[8];
    #pragma unroll
    for (int j = 0; j < 8; j++){
      P[j] = b2f(chP[(size_t)(k + j) * 16384 + id]);
      E[j] = b2f(chH[(size_t)(k + j) * 16384 + id]);
    }
    #pragma unroll
    for (int j = 0; j < 8; j++){
      hin[(size_t)(k + j) * 16384 + id] = f2b(h);
      h = P[j] * h + E[j];
    }
  }
}

__global__ __launch_bounds__(256) void scan_pass3(const u16* __restrict__ dt,
    const u16* xc, const u16* __restrict__ dbc,
    const float* __restrict__ alog, const int* __restrict__ flag,
    const u16* __restrict__ hin,
    const float* __restrict__ dskip, const u16* __restrict__ zsil, u16* yb){
  __shared__ float sBC[LC * 32];
  const int chunk = blockIdx.x;
  const int d = blockIdx.y * 256 + threadIdx.x;
  const int t0 = chunk * LC;
  for (int i = threadIdx.x; i < LC * 32; i += 256){
    int t = i >> 5, c = i & 31;
    sBC[i] = b2f(dbc[(size_t)(t0 + t) * 64 + 32 + c]);
  }
  __syncthreads();
  float h[16];
  #pragma unroll
  for (int s = 0; s < 16; s++)
    h[s] = b2f(hin[((size_t)chunk * 16 + s) * 1024 + d]);
  const float Dv = dskip[d];
  const bool fastA = (flag[1] == 0);
  if (fastA){
    const float a0 = -__expf(alog[(size_t)d * 16]);
    for (int t = 0; t < LC; t++){
      float dtv = b2f(dt[(size_t)(t0 + t) * 1024 + d]);
      float xv  = b2f(xc[(size_t)(t0 + t) * 1024 + d]);
      float dtx = dtv * xv;
      float r = __expf(dtv * a0);
      float a_[16];
      pow16(r, a_);
      float y = 0.f;
      #pragma unroll
      for (int s = 0; s < 16; s++){
        h[s] = a_[s] * h[s] + dtx * sBC[t * 32 + s];
        y += h[s] * sBC[t * 32 + 16 + s];
      }
      float rv = (y + xv * Dv) * b2f(zsil[(size_t)(t0 + t) * 1024 + d]);
      yb[(size_t)(t0 + t) * 1024 + d] = f2b(rv);
    }
  } else {
    float A[16];
    #pragma unroll
    for (int s = 0; s < 16; s++) A[s] = -__expf(alog[(size_t)d * 16 + s]);
    for (int t = 0; t < LC; t++){
      float dtv = b2f(dt[(size_t)(t0 + t) * 1024 + d]);
      float xv  = b2f(xc[(size_t)(t0 + t) * 1024 + d]);
      float dtx = dtv * xv;
      float y = 0.f;
      #pragma unroll
      for (int s = 0; s < 16; s++){
        float a = __expf(dtv * A[s]);
        h[s] = a * h[s] + dtx * sBC[t * 32 + s];
        y += h[s] * sBC[t * 32 + 16 + s];
      }
      float rv = (y + xv * Dv) * b2f(zsil[(size_t)(t0 + t) * 1024 + d]);
      yb[(size_t)(t0 + t) * 1024 + d] = f2b(rv);
    }
  }
}

// final: out[i] = xfin[inverse[i]] — fp32, sole d_out writer.
__global__ __launch_bounds__(256) void final_gather(const float* __restrict__ xfin,
    const void* inv, const int* flag, float* __restrict__ out){
  const bool is64 = flag[0] != 0;
  int i = blockIdx.x, tid = threadIdx.x;
  int src = ldix(inv, i, is64);
  out[(size_t)i * 512 + tid]       = xfin[(size_t)src * 512 + tid];
  out[(size_t)i * 512 + tid + 256] = xfin[(size_t)src * 512 + tid + 256];
}

// ---------------------------------------------------------------------------
extern "C" void kernel_launch(void* const* d_in, const int* in_sizes, int n_in,
                              void* d_out, int out_size, void* d_ws, size_t ws_size,
                              hipStream_t stream){
  float* out = (float*)d_out;
  char* w = (char*)d_ws;

  // ws layout (bytes). chP/chH (8MB each) on dead x1b region.
  constexpr size_t OFF_W1T  = 3342336;
  constexpr size_t OFF_W2T  = OFF_W1T + 1048576;
  constexpr size_t OFF_FLAG = OFF_W2T + 1048576;
  constexpr size_t OFF_XMB  = 5439744;               // 32MiB xmb / dtb / x(fp32)
  constexpr size_t OFF_ZSIL = OFF_XMB  + 33554432;   // 32MiB zsil / midb
  constexpr size_t OFF_XCB  = OFF_ZSIL + 33554432;   // 32MiB xcb / yb / xfin(fp32)
  constexpr size_t OFF_X1B  = OFF_XCB  + 33554432;   // 16MiB x1b / h2b / chP+chH
  constexpr size_t OFF_DBC  = OFF_X1B  + 16777216;   //  2MiB
  constexpr size_t OFF_CHP  = OFF_X1B;               //  8MiB (over dead x1b)
  constexpr size_t OFF_CHH  = OFF_X1B  + 8388608;    //  8MiB
  constexpr size_t WS_NEED  = OFF_DBC  + 2097152;

  int code = 0;
  static const int want[20] = {8388608,16384,16384,512,512,1048576,4096,1024,
                               65536,32768,1024,16384,1024,524288,512,512,
                               524288,1024,524288,512};
  if (n_in != 20) code = 1000;
  else {
    for (int i = 0; i < 20 && !code; i++)
      if (in_sizes[i] != want[i]) code = 2000 + i * 50;
    if (!code && out_size != 8388608) code = 3000;
    if (!code && ws_size < WS_NEED)   code = 4000;
  }
  if (code){
    unsigned n = (unsigned)(out_size > 0 ? out_size : 1);
    fill_k<<<(n + 255) / 256, 256, 0, stream>>>(out, (float)code, n);
    return;
  }

  u16*   w1tb = (u16*)(w + OFF_W1T);
  u16*   w2tb = (u16*)(w + OFF_W2T);
  int*   flag = (int*)(w + OFF_FLAG);
  u16*   xmb  = (u16*)(w + OFF_XMB);
  u16*   zsil = (u16*)(w + OFF_ZSIL);
  u16*   xcb  = (u16*)(w + OFF_XCB);
  u16*   x1b  = (u16*)(w + OFF_X1B);
  u16*   dbcb = (u16*)(w + OFF_DBC);
  u16*   chP  = (u16*)(w + OFF_CHP);
  u16*   chH  = (u16*)(w + OFF_CHH);
  float* x    = (float*)(w + OFF_XMB);   // fp32 residual over dead dtb
  float* xfin = (float*)(w + OFF_XCB);   // fp32 final (pre-inverse), over dead yb
  u16* dtb  = xmb;   // xmb dead after conv
  u16* yb   = xcb;   // pass3: read-before-write per element
  u16* midb = zsil;  // zsil dead after pass3
  u16* h2b  = x1b;   // x1b dead after in_proj (and chP/chH dead after pass3)
  u16* hin  = chP;   // carry: read-before-write per window

  // bf16-packed GEMM weights at ws offset 0 (element offsets)
  u16* nb = (u16*)w;
  u16* inpjn  = nb;
  u16* xpjn   = nb + 1048576;
  u16* dtpjn  = nb + 1114112;
  u16* outpjn = nb + 1146880;
  NT4 t;
  t.src[0] = (const float*)d_in[5];  t.src[1] = (const float*)d_in[8];
  t.src[2] = (const float*)d_in[9];  t.src[3] = (const float*)d_in[13];
  t.off[0] = 0; t.off[1] = 1048576; t.off[2] = 1114112; t.off[3] = 1146880; t.off[4] = 1671168;

  detect_k<<<1, 1, 0, stream>>>((const int*)d_in[1], flag);
  checkA_k<<<64, 256, 0, stream>>>((const float*)d_in[11], flag);
  normw_k<<<(1671168 + 255) / 256, 256, 0, stream>>>(t, nb);
  convT_kernel<<<dim3(16, 32), 256, 0, stream>>>((const float*)d_in[16], w1tb, 512, 1024);
  convT_kernel<<<dim3(32, 16), 256, 0, stream>>>((const float*)d_in[18], w2tb, 1024, 512);

  // 1. gather + LN1
  gather_ln1<<<L_SEQ, 256, 0, stream>>>((const float*)d_in[0], d_in[1],
      (const float*)d_in[3], (const float*)d_in[4], flag, x1b);

  // 2. in_proj -> xmb | silu(z)   (K=512, 16 pipelined steps)
  gemm_p2<128,128,64,64,M_INPROJ><<<dim3(128,16),256,0,stream>>>(
      x1b, inpjn, 2048, 512, 512, 512, nullptr, xmb, zsil, nullptr, nullptr, nullptr, nullptr);

  // 3. conv + silu
  conv_silu<<<1024, 256, 0, stream>>>(xmb,
      (const float*)d_in[6], (const float*)d_in[7], xcb);

  // 4. x_proj -> dbcb   (K=1024, 32 pipelined steps)
  gemm_p2<64,64,16,64,M_BF16><<<dim3(256,1),256,0,stream>>>(
      xcb, xpjn, 64, 1024, 1024, 1024, nullptr, dbcb, nullptr, nullptr, nullptr, nullptr, nullptr);

  // 5. dt_proj + softplus -> dtb  (K=32: single step, legacy kernel)
  gemm_bt<128,128,64,64,M_DT><<<dim3(128,8),256,0,stream>>>(
      dbcb, dtpjn, 1024, 32, 64, 32, nullptr, dtb, nullptr, nullptr,
      (const float*)d_in[10], nullptr, nullptr);

  // 6. chunked scan
  scan_pass1<<<dim3(NCH,4),256,0,stream>>>(dtb, xcb, dbcb,
      (const float*)d_in[11], flag, chP, chH);
  carry_scan<<<256,64,0,stream>>>(chP, chH, hin);
  scan_pass3<<<dim3(NCH,4),256,0,stream>>>(dtb, xcb, dbcb,
      (const float*)d_in[11], flag, hin, (const float*)d_in[12], zsil, yb);

  // 7. out_proj + feat[order[m]] residual -> x (fp32)  (K=1024)
  gemm_p2<128,128,64,64,M_RES><<<dim3(128,4),256,0,stream>>>(
      yb, outpjn, 512, 1024, 1024, 1024, x, nullptr, nullptr, nullptr,
      (const float*)d_in[0], d_in[1], flag);

  // 8. LN2 -> h2b
  ln2_kernel<<<L_SEQ,256,0,stream>>>(x, (const float*)d_in[14], (const float*)d_in[15], h2b);

  // 9. FFN1 + gelu -> midb  (K=512)
  gemm_p2<128,128,64,64,M_GELU><<<dim3(128,8),256,0,stream>>>(
      h2b, w1tb, 1024, 512, 512, 512, nullptr, midb, nullptr, nullptr,
      (const float*)d_in[17], nullptr, nullptr);

  // 10. FFN2 + bias + residual -> xfin (fp32, serialized order)  (K=1024)
  gemm_p2<128,128,64,64,M_FFN2><<<dim3(128,4),256,0,stream>>>(
      midb, w2tb, 512, 1024, 1024, 1024, xfin, nullptr, nullptr, x,
      (const float*)d_in[19], nullptr, nullptr);

  // 11. out[i] = xfin[inverse[i]]  (fp32)
  final_gather<<<L_SEQ,256,0,stream>>>(xfin, d_in[2], flag, out);
}

// Round 6
// 503.940 us; speedup vs baseline: 1.4534x; 1.4534x over previous
//
#include <hip/hip_runtime.h>

// SerializedMamba on MI355X (gfx950).
// R17: dt_proj softplus fix. R16 exposed gemm_bt(dt_proj) at 159us with
//      MfmaUtil 0.26% (MFMA work ~0.5us -- consistent) and VALUBusy 35%
//      (~55us of VALU issue): 16.7M log1pf libm calls (~50 ops, branchy).
//      dt_proj has been hiding just under every round's top-5 cutoff.
//      Fix: branch-free softplus = max(x,0) + __logf(1+__expf(-|x|))
//      (7 VALU ops, v_exp/v_log single-instr). Everything else = R16:
//      gemm_p2 depth-2 pipeline, counted vmcnt, 2-way LDS bijection,
//      natural block dispatch (no XCD swizzle).
// R13: conv_silu vectorized rolling window; gld_lds width=16 staging.
// R12: scan LC=64/NCH=256, fast-path exp power chain (checkA_k-verified).

#define DEV __device__ __forceinline__

typedef unsigned short u16;
typedef u16    u16x8  __attribute__((ext_vector_type(8)));
typedef __bf16 bf16x8 __attribute__((ext_vector_type(8)));
typedef float  f32x4  __attribute__((ext_vector_type(4)));

static constexpr int L_SEQ = 16384;
static constexpr int LC    = 64;    // scan chunk length
static constexpr int NCH   = 256;   // number of chunks

DEV u16 f2b(float x){
  union { float f; unsigned u; } c; c.f = x;
  unsigned u = c.u;
  return (u16)((u + 0x7fffu + ((u >> 16) & 1u)) >> 16);   // RNE
}
DEV float b2f(u16 h){
  union { unsigned u; float f; } c; c.u = ((unsigned)h) << 16;
  return c.f;
}
DEV int ldix(const void* p, int l, bool is64){
  return is64 ? (int)((const long long*)p)[l] : ((const int*)p)[l];
}
DEV float siluf(float x){ return x / (1.f + __expf(-x)); }
// branch-free: log(1+e^x) = max(x,0) + log(1+e^-|x|); v_exp+v_log intrinsics
DEV float softplusf(float x){
  return fmaxf(x, 0.f) + __logf(1.f + __expf(-fabsf(x)));
}
DEV float geluf(float x){ return 0.5f * x * (1.f + erff(x * 0.70710678118f)); }

// direct global->LDS async copy, 16B per lane (dest must be wave-uniform
// base + lane*16 -- holds for linear tid*16 layouts)
DEV void gld_lds16(const u16* g, u16* l){
  __builtin_amdgcn_global_load_lds(
      (const __attribute__((address_space(1))) unsigned*)g,
      (__attribute__((address_space(3))) unsigned*)l, 16, 0, 0);
}

// r^(s+1) for s=0..15 via log-depth power chain (15 muls after r2/r4/r8)
DEV void pow16(float r, float* a){
  float r2 = r * r, r4 = r2 * r2, r8 = r4 * r4;
  a[0] = r;        a[1] = r2;       a[2] = r2 * r;    a[3] = r4;
  a[4] = r4 * r;   a[5] = r4 * r2;  a[6] = r4 * a[2]; a[7] = r8;
  a[8] = r8 * r;   a[9] = r8 * r2;  a[10] = r8 * a[2]; a[11] = r8 * r4;
  a[12] = r8 * a[4]; a[13] = r8 * a[5]; a[14] = r8 * a[6]; a[15] = r8 * r8;
}

// ---------------------------------------------------------------------------
__global__ __launch_bounds__(256) void fill_k(float* out, float v, unsigned n){
  unsigned i = blockIdx.x * 256 + threadIdx.x;
  if (i < n) out[i] = v;
}

// flag[0]: index inputs are int64. flag[1]: A-structure mismatch (checkA_k).
__global__ void detect_k(const int* ord32, int* flag){
  flag[0] = (ord32[1] == 0 && ord32[3] == 0 && ord32[5] == 0) ? 1 : 0;
  flag[1] = 0;
}

// verify A_log[d][s] == A_log[d][0] + log(s+1)  (=> A[s] = A[0]*(s+1))
__global__ __launch_bounds__(256) void checkA_k(const float* __restrict__ alog,
                                                int* flag){
  int i = blockIdx.x * 256 + threadIdx.x;   // 16384 = d*16+s
  int s = i & 15;
  float v = alog[i];
  float base = alog[i - s];
  if (fabsf(v - (base + __logf((float)(s + 1)))) > 1e-4f) atomicOr(flag + 1, 1);
}

// fp32 -> bf16 pack of the 4 B^T-layout GEMM weights (dense at ws offset 0)
struct NT4 { const float* src[4]; unsigned off[5]; };
__global__ __launch_bounds__(256) void normw_k(NT4 t, u16* dst){
  unsigned i = blockIdx.x * 256 + threadIdx.x;
  if (i >= t.off[4]) return;
  int s = 0;
  #pragma unroll
  for (int k = 1; k <= 3; k++) s += (i >= t.off[k]) ? 1 : 0;
  dst[i] = f2b(t.src[s][i - t.off[s]]);
}

// transpose-convert: out[n*K + k] = f2b(in[k*N + n])
__global__ __launch_bounds__(256) void convT_kernel(const float* __restrict__ in,
                                                    u16* __restrict__ out, int K, int N){
  __shared__ float t[32][33];
  int k0 = blockIdx.x * 32, n0 = blockIdx.y * 32;
  int tx = threadIdx.x & 31, ty = threadIdx.x >> 5;
  #pragma unroll
  for (int i = 0; i < 32; i += 8)
    t[ty + i][tx] = in[(size_t)(k0 + ty + i) * N + n0 + tx];
  __syncthreads();
  #pragma unroll
  for (int i = 0; i < 32; i += 8)
    out[(size_t)(n0 + ty + i) * K + k0 + tx] = f2b(t[tx][ty + i]);
}

// ---------------------------------------------------------------------------
// layernorms (C=512, one block/row, LDS tree)
// ---------------------------------------------------------------------------
__global__ __launch_bounds__(256) void gather_ln1(const float* __restrict__ feat,
    const void* order, const float* __restrict__ w, const float* __restrict__ b,
    const int* flag, u16* __restrict__ x1b){
  __shared__ float rs_[256], rq_[256];
  const bool is64 = flag[0] != 0;
  int l = blockIdx.x, tid = threadIdx.x;
  int src = ldix(order, l, is64);
  float v0 = feat[(size_t)src * 512 + tid];
  float v1 = feat[(size_t)src * 512 + tid + 256];
  rs_[tid] = v0 + v1; rq_[tid] = v0 * v0 + v1 * v1;
  __syncthreads();
  for (int o = 128; o; o >>= 1){
    if (tid < o){ rs_[tid] += rs_[tid + o]; rq_[tid] += rq_[tid + o]; }
    __syncthreads();
  }
  float mu = rs_[0] * (1.f / 512.f);
  float var = rq_[0] * (1.f / 512.f) - mu * mu;
  float rstd = rsqrtf(var + 1e-5f);
  x1b[(size_t)l * 512 + tid]       = f2b((v0 - mu) * rstd * w[tid]       + b[tid]);
  x1b[(size_t)l * 512 + tid + 256] = f2b((v1 - mu) * rstd * w[tid + 256] + b[tid + 256]);
}

__global__ __launch_bounds__(256) void ln2_kernel(const float* __restrict__ x,
    const float* __restrict__ w, const float* __restrict__ b, u16* __restrict__ h2b){
  __shared__ float rs_[256], rq_[256];
  int l = blockIdx.x, tid = threadIdx.x;
  float v0 = x[(size_t)l * 512 + tid];
  float v1 = x[(size_t)l * 512 + tid + 256];
  rs_[tid] = v0 + v1; rq_[tid] = v0 * v0 + v1 * v1;
  __syncthreads();
  for (int o = 128; o; o >>= 1){
    if (tid < o){ rs_[tid] += rs_[tid + o]; rq_[tid] += rq_[tid + o]; }
    __syncthreads();
  }
  float mu = rs_[0] * (1.f / 512.f);
  float var = rq_[0] * (1.f / 512.f) - mu * mu;
  float rstd = rsqrtf(var + 1e-5f);
  h2b[(size_t)l * 512 + tid]       = f2b((v0 - mu) * rstd * w[tid]       + b[tid]);
  h2b[(size_t)l * 512 + tid + 256] = f2b((v1 - mu) * rstd * w[tid + 256] + b[tid + 256]);
}

// ---------------------------------------------------------------------------
// depthwise causal conv (k=4) + silu -- vectorized rolling window.
// ---------------------------------------------------------------------------
__global__ __launch_bounds__(256) void conv_silu(const u16* __restrict__ xm,
    const float* __restrict__ cw, const float* __restrict__ cb, u16* __restrict__ xcb){
  constexpr int TT = 8;
  const int tid = threadIdx.x;
  const int d0 = (tid & 127) * 8;
  const int t0 = (blockIdx.x * 2 + (tid >> 7)) * TT;

  float wk[4][8], bias[8];
  #pragma unroll
  for (int j = 0; j < 8; j++) bias[j] = cb[d0 + j];
  #pragma unroll
  for (int j = 0; j < 8; j++){
    f32x4 v = *(const f32x4*)(cw + (d0 + j) * 4);
    wk[0][j] = v[0]; wk[1][j] = v[1]; wk[2][j] = v[2]; wk[3][j] = v[3];
  }

  float win[3][8];
  #pragma unroll
  for (int k = 0; k < 3; k++){
    int tt = t0 - 3 + k;
    if (tt >= 0){
      u16x8 v = *(const u16x8*)(xm + (size_t)tt * 1024 + d0);
      #pragma unroll
      for (int j = 0; j < 8; j++) win[k][j] = b2f(v[j]);
    } else {
      #pragma unroll
      for (int j = 0; j < 8; j++) win[k][j] = 0.f;
    }
  }

  #pragma unroll
  for (int t = 0; t < TT; t++){
    u16x8 v = *(const u16x8*)(xm + (size_t)(t0 + t) * 1024 + d0);
    u16x8 o;
    float cu[8];
    #pragma unroll
    for (int j = 0; j < 8; j++){
      cu[j] = b2f(v[j]);
      float acc = bias[j] + win[0][j] * wk[0][j] + win[1][j] * wk[1][j]
                + win[2][j] * wk[2][j] + cu[j] * wk[3][j];
      o[j] = f2b(siluf(acc));
    }
    *(u16x8*)(xcb + (size_t)(t0 + t) * 1024 + d0) = o;
    #pragma unroll
    for (int j = 0; j < 8; j++){
      win[0][j] = win[1][j]; win[1][j] = win[2][j]; win[2][j] = cu[j];
    }
  }
}

// ---------------------------------------------------------------------------
// bf16 MFMA GEMM, C = A (MxK, lda) * B^T (NxK, ldb), fused epilogues.
// ---------------------------------------------------------------------------
enum { M_BF16 = 0, M_INPROJ = 1, M_DT = 2, M_RES = 3, M_GELU = 4, M_FFN2 = 5 };

template<int MODE>
DEV void gemm_epilogue(float v, int m, int n, int N,
    float* __restrict__ outf, u16* __restrict__ outb, u16* __restrict__ outb2,
    const float* __restrict__ auxf, const float* __restrict__ auxw,
    const void* ordv, bool is64){
  size_t o = (size_t)m * N + n;
  if constexpr (MODE == M_BF16){
    outb[o] = f2b(v);
  } else if constexpr (MODE == M_INPROJ){
    if (n < 1024) outb [(size_t)m * 1024 + n]          = f2b(v);
    else          outb2[(size_t)m * 1024 + (n - 1024)] = f2b(siluf(v));
  } else if constexpr (MODE == M_DT){
    outb[o] = f2b(softplusf(v + auxw[n]));
  } else if constexpr (MODE == M_RES){
    int src = ldix(ordv, m, is64);
    outf[o] = v + auxw[(size_t)src * 512 + n];   // + feat[order[m]]
  } else if constexpr (MODE == M_GELU){
    outb[o] = f2b(geluf(v + auxw[n]));
  } else { // M_FFN2: + bias + residual -> fp32 (serialized order)
    outf[o] = v + auxw[n] + auxf[o];
  }
}

// depth-2 pipelined GEMM. BK=32, 3 LDS buffers, counted vmcnt (never 0
// mid-loop), raw barriers. LDS bijection: row's chunk qc lives at slot
// sub = (qc + (row>>1)) & 3  (2-way bank aliasing = free). Stage source uses
// the inverse cg = (sub - (row>>1)) & 3; read uses the forward map (rule #21).
// Requires K % 32 == 0.
template<int BM, int BN, int WM, int WN, int MODE>
__global__ __launch_bounds__(256) void gemm_p2(
    const u16* __restrict__ A, const u16* __restrict__ B,
    int N, int K, int lda, int ldb,
    float* __restrict__ outf, u16* __restrict__ outb, u16* __restrict__ outb2,
    const float* __restrict__ auxf, const float* __restrict__ auxw,
    const void* ordv, const int* flag){
  constexpr int BK = 32;
  constexpr int MI = WM / 16, NI = WN / 16;
  constexpr int WCOLS = BN / WN;
  constexpr int NA = BM * BK / (256 * 8);
  constexpr int NB = BN * BK / (256 * 8);
  constexpr int LPS = NA + NB;               // gld_lds per thread per stage
  static_assert(LPS == 2 || LPS == 4, "vmcnt literals assume LPS in {2,4}");
  __shared__ __align__(16) u16 sA[3][BM * BK];
  __shared__ __align__(16) u16 sB[3][BN * BK];
  const int tid  = threadIdx.x;
  const int wave = tid >> 6, lane = tid & 63;
  const int wr = wave / WCOLS, wc = wave % WCOLS;
  const int m0 = blockIdx.x * BM, n0 = blockIdx.y * BN;   // natural dispatch
  const int rr = lane & 15;          // fragment row within 16
  const int qc = lane >> 4;          // k-chunk 0..3

  f32x4 acc[MI][NI] = {};

  auto stage = [&](int buf, int k0){
    #pragma unroll
    for (int i = 0; i < NA; i++){
      int idx = tid + i * 256;
      int row = idx >> 2, sub = idx & 3;
      int cg = (sub - (row >> 1)) & 3;
      gld_lds16(A + (size_t)(m0 + row) * lda + k0 + cg * 8, &sA[buf][idx * 8]);
    }
    #pragma unroll
    for (int i = 0; i < NB; i++){
      int idx = tid + i * 256;
      int row = idx >> 2, sub = idx & 3;
      int cg = (sub - (row >> 1)) & 3;
      gld_lds16(B + (size_t)(n0 + row) * ldb + k0 + cg * 8, &sB[buf][idx * 8]);
    }
  };

  const int nst = K / BK;
  stage(0, 0);
  if (nst > 1) stage(1, BK);
  for (int st = 0; st < nst; st++){
    if (st + 2 < nst) stage((st + 2) % 3, (st + 2) * BK);
    // wait for MY stage(st): newer stages in flight = nf, each LPS loads
    const int nf = (st + 2 < nst) ? 2 : ((st + 1 < nst) ? 1 : 0);
    if (nf == 2){
      if constexpr (LPS == 4) asm volatile("s_waitcnt vmcnt(8)" ::: "memory");
      else                    asm volatile("s_waitcnt vmcnt(4)" ::: "memory");
    } else if (nf == 1){
      if constexpr (LPS == 4) asm volatile("s_waitcnt vmcnt(4)" ::: "memory");
      else                    asm volatile("s_waitcnt vmcnt(2)" ::: "memory");
    } else {
      asm volatile("s_waitcnt vmcnt(0)" ::: "memory");
    }
    __builtin_amdgcn_s_barrier();        // everyone's stage(st) landed
    __builtin_amdgcn_sched_barrier(0);

    const int cur = st % 3;
    bf16x8 af[MI], bfr[NI];
    #pragma unroll
    for (int i = 0; i < MI; i++){
      int R = wr * WM + i * 16 + rr;
      int slot = (qc + (R >> 1)) & 3;
      af[i] = *(const bf16x8*)(&sA[cur][R * BK + slot * 8]);
    }
    #pragma unroll
    for (int j = 0; j < NI; j++){
      int R = wc * WN + j * 16 + rr;
      int slot = (qc + (R >> 1)) & 3;
      bfr[j] = *(const bf16x8*)(&sB[cur][R * BK + slot * 8]);
    }
    #pragma unroll
    for (int i = 0; i < MI; i++)
      #pragma unroll
      for (int j = 0; j < NI; j++)
        acc[i][j] = __builtin_amdgcn_mfma_f32_16x16x32_bf16(af[i], bfr[j], acc[i][j], 0, 0, 0);

    asm volatile("s_waitcnt lgkmcnt(0)" ::: "memory");
    __builtin_amdgcn_s_barrier();        // all reads of buf[cur] done before
    __builtin_amdgcn_sched_barrier(0);   // next iter's stage overwrites it
  }

  const bool is64 = flag ? (flag[0] != 0) : false;
  // D layout: col(N) = lane&15, row(M) = (lane>>4)*4 + r   [m89-verified]
  #pragma unroll
  for (int i = 0; i < MI; i++)
    #pragma unroll
    for (int j = 0; j < NI; j++)
      #pragma unroll
      for (int r = 0; r < 4; r++){
        int m = m0 + wr * WM + i * 16 + ((lane >> 4) << 2) + r;
        int n = n0 + wc * WN + j * 16 + (lane & 15);
        gemm_epilogue<MODE>(acc[i][j][r], m, n, N, outf, outb, outb2,
                            auxf, auxw, ordv, is64);
      }
}

// Legacy BK=32 single-buffer variant (kept for dt_proj, K=32: single step).
template<int BM, int BN, int WM, int WN, int MODE>
__global__ __launch_bounds__(256) void gemm_bt(
    const u16* __restrict__ A, const u16* __restrict__ B,
    int N, int K, int lda, int ldb,
    float* __restrict__ outf, u16* __restrict__ outb, u16* __restrict__ outb2,
    const float* __restrict__ auxf, const float* __restrict__ auxw,
    const void* ordv, const int* flag){
  constexpr int BK = 32;
  constexpr int MI = WM / 16, NI = WN / 16;
  constexpr int WCOLS = BN / WN;
  constexpr int NA = BM * 4 / 256;
  constexpr int NB = BN * 4 / 256;
  __shared__ __align__(16) u16 sA[BM * BK];
  __shared__ __align__(16) u16 sB[BN * BK];
  const int tid  = threadIdx.x;
  const int wave = tid >> 6, lane = tid & 63;
  const int wr = wave / WCOLS, wc = wave % WCOLS;
  const int m0 = blockIdx.x * BM, n0 = blockIdx.y * BN;
  const int rr = lane & 15;
  const int qk = (lane >> 4) * 8;

  f32x4 acc[MI][NI] = {};

  for (int k0 = 0; k0 < K; k0 += BK){
    #pragma unroll
    for (int i = 0; i < NA; i++){
      int idx = tid + i * 256;
      int r = idx >> 2, c = (idx & 3) * 8;
      gld_lds16(A + (size_t)(m0 + r) * lda + k0 + c, sA + (size_t)idx * 8);
    }
    #pragma unroll
    for (int i = 0; i < NB; i++){
      int idx = tid + i * 256;
      int r = idx >> 2, c = (idx & 3) * 8;
      gld_lds16(B + (size_t)(n0 + r) * ldb + k0 + c, sB + (size_t)idx * 8);
    }
    __syncthreads();

    bf16x8 af[MI], bfr[NI];
    #pragma unroll
    for (int i = 0; i < MI; i++)
      af[i] = *(const bf16x8*)(sA + (wr * WM + i * 16 + rr) * BK + qk);
    #pragma unroll
    for (int j = 0; j < NI; j++)
      bfr[j] = *(const bf16x8*)(sB + (wc * WN + j * 16 + rr) * BK + qk);
    #pragma unroll
    for (int i = 0; i < MI; i++)
      #pragma unroll
      for (int j = 0; j < NI; j++)
        acc[i][j] = __builtin_amdgcn_mfma_f32_16x16x32_bf16(af[i], bfr[j], acc[i][j], 0, 0, 0);
    __syncthreads();
  }

  const bool is64 = flag ? (flag[0] != 0) : false;
  #pragma unroll
  for (int i = 0; i < MI; i++)
    #pragma unroll
    for (int j = 0; j < NI; j++)
      #pragma unroll
      for (int r = 0; r < 4; r++){
        int m = m0 + wr * WM + i * 16 + ((lane >> 4) << 2) + r;
        int n = n0 + wc * WN + j * 16 + (lane & 15);
        gemm_epilogue<MODE>(acc[i][j][r], m, n, N, outf, outb, outb2,
                            auxf, auxw, ordv, is64);
      }
}

// ---------------------------------------------------------------------------
// chunked selective scan (fp32 state; chP/chH bf16, layout [chunk][s][d])
// ---------------------------------------------------------------------------
__global__ __launch_bounds__(256) void scan_pass1(const u16* __restrict__ dt,
    const u16* __restrict__ xc, const u16* __restrict__ dbc,
    const float* __restrict__ alog, const int* __restrict__ flag,
    u16* __restrict__ chP, u16* __restrict__ chH){
  __shared__ float sB[LC * 16];
  const int chunk = blockIdx.x;
  const int d = blockIdx.y * 256 + threadIdx.x;
  const int t0 = chunk * LC;
  for (int i = threadIdx.x; i < LC * 16; i += 256){
    int t = i >> 4, s = i & 15;
    sB[i] = b2f(dbc[(size_t)(t0 + t) * 64 + 32 + s]);
  }
  __syncthreads();
  float h[16];
  #pragma unroll
  for (int s = 0; s < 16; s++) h[s] = 0.f;
  float P[16];
  const bool fastA = (flag[1] == 0);
  if (fastA){
    const float a0 = -__expf(alog[(size_t)d * 16]);
    float R = 1.f;
    for (int t = 0; t < LC; t++){
      float dtv = b2f(dt[(size_t)(t0 + t) * 1024 + d]);
      float xv  = b2f(xc[(size_t)(t0 + t) * 1024 + d]);
      float dtx = dtv * xv;
      float r = __expf(dtv * a0);
      R *= r;
      float a_[16];
      pow16(r, a_);
      #pragma unroll
      for (int s = 0; s < 16; s++)
        h[s] = a_[s] * h[s] + dtx * sB[t * 16 + s];
    }
    pow16(R, P);
  } else {
    float A[16];
    #pragma unroll
    for (int s = 0; s < 16; s++){
      A[s] = -__expf(alog[(size_t)d * 16 + s]);
      P[s] = 1.f;
    }
    for (int t = 0; t < LC; t++){
      float dtv = b2f(dt[(size_t)(t0 + t) * 1024 + d]);
      float xv  = b2f(xc[(size_t)(t0 + t) * 1024 + d]);
      float dtx = dtv * xv;
      #pragma unroll
      for (int s = 0; s < 16; s++){
        float a = __expf(dtv * A[s]);
        P[s] *= a;
        h[s] = a * h[s] + dtx * sB[t * 16 + s];
      }
    }
  }
  #pragma unroll
  for (int s = 0; s < 16; s++){
    chP[((size_t)chunk * 16 + s) * 1024 + d] = f2b(P[s]);   // coalesced over d
    chH[((size_t)chunk * 16 + s) * 1024 + d] = f2b(h[s]);
  }
}

// hin may alias chP: window loads 8 ahead into regs before storing.
__global__ __launch_bounds__(64) void carry_scan(const u16* chP, const u16* chH,
                                                 u16* hin){
  int id = blockIdx.x * 64 + threadIdx.x;   // id = s*1024 + d
  float h = 0.f;
  for (int k = 0; k < NCH; k += 8){
    float P[8], E[8];
    #pragma unroll
    for (int j = 0; j < 8; j++){
      P[j] = b2f(chP[(size_t)(k + j) * 16384 + id]);
      E[j] = b2f(chH[(size_t)(k + j) * 16384 + id]);
    }
    #pragma unroll
    for (int j = 0; j < 8; j++){
      hin[(size_t)(k + j) * 16384 + id] = f2b(h);
      h = P[j] * h + E[j];
    }
  }
}

__global__ __launch_bounds__(256) void scan_pass3(const u16* __restrict__ dt,
    const u16* xc, const u16* __restrict__ dbc,
    const float* __restrict__ alog, const int* __restrict__ flag,
    const u16* __restrict__ hin,
    const float* __restrict__ dskip, const u16* __restrict__ zsil, u16* yb){
  __shared__ float sBC[LC * 32];
  const int chunk = blockIdx.x;
  const int d = blockIdx.y * 256 + threadIdx.x;
  const int t0 = chunk * LC;
  for (int i = threadIdx.x; i < LC * 32; i += 256){
    int t = i >> 5, c = i & 31;
    sBC[i] = b2f(dbc[(size_t)(t0 + t) * 64 + 32 + c]);
  }
  __syncthreads();
  float h[16];
  #pragma unroll
  for (int s = 0; s < 16; s++)
    h[s] = b2f(hin[((size_t)chunk * 16 + s) * 1024 + d]);
  const float Dv = dskip[d];
  const bool fastA = (flag[1] == 0);
  if (fastA){
    const float a0 = -__expf(alog[(size_t)d * 16]);
    for (int t = 0; t < LC; t++){
      float dtv = b2f(dt[(size_t)(t0 + t) * 1024 + d]);
      float xv  = b2f(xc[(size_t)(t0 + t) * 1024 + d]);
      float dtx = dtv * xv;
      float r = __expf(dtv * a0);
      float a_[16];
      pow16(r, a_);
      float y = 0.f;
      #pragma unroll
      for (int s = 0; s < 16; s++){
        h[s] = a_[s] * h[s] + dtx * sBC[t * 32 + s];
        y += h[s] * sBC[t * 32 + 16 + s];
      }
      float rv = (y + xv * Dv) * b2f(zsil[(size_t)(t0 + t) * 1024 + d]);
      yb[(size_t)(t0 + t) * 1024 + d] = f2b(rv);
    }
  } else {
    float A[16];
    #pragma unroll
    for (int s = 0; s < 16; s++) A[s] = -__expf(alog[(size_t)d * 16 + s]);
    for (int t = 0; t < LC; t++){
      float dtv = b2f(dt[(size_t)(t0 + t) * 1024 + d]);
      float xv  = b2f(xc[(size_t)(t0 + t) * 1024 + d]);
      float dtx = dtv * xv;
      float y = 0.f;
      #pragma unroll
      for (int s = 0; s < 16; s++){
        float a = __expf(dtv * A[s]);
        h[s] = a * h[s] + dtx * sBC[t * 32 + s];
        y += h[s] * sBC[t * 32 + 16 + s];
      }
      float rv = (y + xv * Dv) * b2f(zsil[(size_t)(t0 + t) * 1024 + d]);
      yb[(size_t)(t0 + t) * 1024 + d] = f2b(rv);
    }
  }
}

// final: out[i] = xfin[inverse[i]] — fp32, sole d_out writer.
__global__ __launch_bounds__(256) void final_gather(const float* __restrict__ xfin,
    const void* inv, const int* flag, float* __restrict__ out){
  const bool is64 = flag[0] != 0;
  int i = blockIdx.x, tid = threadIdx.x;
  int src = ldix(inv, i, is64);
  out[(size_t)i * 512 + tid]       = xfin[(size_t)src * 512 + tid];
  out[(size_t)i * 512 + tid + 256] = xfin[(size_t)src * 512 + tid + 256];
}

// ---------------------------------------------------------------------------
extern "C" void kernel_launch(void* const* d_in, const int* in_sizes, int n_in,
                              void* d_out, int out_size, void* d_ws, size_t ws_size,
                              hipStream_t stream){
  float* out = (float*)d_out;
  char* w = (char*)d_ws;

  // ws layout (bytes). chP/chH (8MB each) on dead x1b region.
  constexpr size_t OFF_W1T  = 3342336;
  constexpr size_t OFF_W2T  = OFF_W1T + 1048576;
  constexpr size_t OFF_FLAG = OFF_W2T + 1048576;
  constexpr size_t OFF_XMB  = 5439744;               // 32MiB xmb / dtb / x(fp32)
  constexpr size_t OFF_ZSIL = OFF_XMB  + 33554432;   // 32MiB zsil / midb
  constexpr size_t OFF_XCB  = OFF_ZSIL + 33554432;   // 32MiB xcb / yb / xfin(fp32)
  constexpr size_t OFF_X1B  = OFF_XCB  + 33554432;   // 16MiB x1b / h2b / chP+chH
  constexpr size_t OFF_DBC  = OFF_X1B  + 16777216;   //  2MiB
  constexpr size_t OFF_CHP  = OFF_X1B;               //  8MiB (over dead x1b)
  constexpr size_t OFF_CHH  = OFF_X1B  + 8388608;    //  8MiB
  constexpr size_t WS_NEED  = OFF_DBC  + 2097152;

  int code = 0;
  static const int want[20] = {8388608,16384,16384,512,512,1048576,4096,1024,
                               65536,32768,1024,16384,1024,524288,512,512,
                               524288,1024,524288,512};
  if (n_in != 20) code = 1000;
  else {
    for (int i = 0; i < 20 && !code; i++)
      if (in_sizes[i] != want[i]) code = 2000 + i * 50;
    if (!code && out_size != 8388608) code = 3000;
    if (!code && ws_size < WS_NEED)   code = 4000;
  }
  if (code){
    unsigned n = (unsigned)(out_size > 0 ? out_size : 1);
    fill_k<<<(n + 255) / 256, 256, 0, stream>>>(out, (float)code, n);
    return;
  }

  u16*   w1tb = (u16*)(w + OFF_W1T);
  u16*   w2tb = (u16*)(w + OFF_W2T);
  int*   flag = (int*)(w + OFF_FLAG);
  u16*   xmb  = (u16*)(w + OFF_XMB);
  u16*   zsil = (u16*)(w + OFF_ZSIL);
  u16*   xcb  = (u16*)(w + OFF_XCB);
  u16*   x1b  = (u16*)(w + OFF_X1B);
  u16*   dbcb = (u16*)(w + OFF_DBC);
  u16*   chP  = (u16*)(w + OFF_CHP);
  u16*   chH  = (u16*)(w + OFF_CHH);
  float* x    = (float*)(w + OFF_XMB);   // fp32 residual over dead dtb
  float* xfin = (float*)(w + OFF_XCB);   // fp32 final (pre-inverse), over dead yb
  u16* dtb  = xmb;   // xmb dead after conv
  u16* yb   = xcb;   // pass3: read-before-write per element
  u16* midb = zsil;  // zsil dead after pass3
  u16* h2b  = x1b;   // x1b dead after in_proj (and chP/chH dead after pass3)
  u16* hin  = chP;   // carry: read-before-write per window

  // bf16-packed GEMM weights at ws offset 0 (element offsets)
  u16* nb = (u16*)w;
  u16* inpjn  = nb;
  u16* xpjn   = nb + 1048576;
  u16* dtpjn  = nb + 1114112;
  u16* outpjn = nb + 1146880;
  NT4 t;
  t.src[0] = (const float*)d_in[5];  t.src[1] = (const float*)d_in[8];
  t.src[2] = (const float*)d_in[9];  t.src[3] = (const float*)d_in[13];
  t.off[0] = 0; t.off[1] = 1048576; t.off[2] = 1114112; t.off[3] = 1146880; t.off[4] = 1671168;

  detect_k<<<1, 1, 0, stream>>>((const int*)d_in[1], flag);
  checkA_k<<<64, 256, 0, stream>>>((const float*)d_in[11], flag);
  normw_k<<<(1671168 + 255) / 256, 256, 0, stream>>>(t, nb);
  convT_kernel<<<dim3(16, 32), 256, 0, stream>>>((const float*)d_in[16], w1tb, 512, 1024);
  convT_kernel<<<dim3(32, 16), 256, 0, stream>>>((const float*)d_in[18], w2tb, 1024, 512);

  // 1. gather + LN1
  gather_ln1<<<L_SEQ, 256, 0, stream>>>((const float*)d_in[0], d_in[1],
      (const float*)d_in[3], (const float*)d_in[4], flag, x1b);

  // 2. in_proj -> xmb | silu(z)   (K=512, 16 pipelined steps)
  gemm_p2<128,128,64,64,M_INPROJ><<<dim3(128,16),256,0,stream>>>(
      x1b, inpjn, 2048, 512, 512, 512, nullptr, xmb, zsil, nullptr, nullptr, nullptr, nullptr);

  // 3. conv + silu
  conv_silu<<<1024, 256, 0, stream>>>(xmb,
      (const float*)d_in[6], (const float*)d_in[7], xcb);

  // 4. x_proj -> dbcb   (K=1024, 32 pipelined steps)
  gemm_p2<64,64,16,64,M_BF16><<<dim3(256,1),256,0,stream>>>(
      xcb, xpjn, 64, 1024, 1024, 1024, nullptr, dbcb, nullptr, nullptr, nullptr, nullptr, nullptr);

  // 5. dt_proj + softplus -> dtb  (K=32: single step, legacy kernel)
  gemm_bt<128,128,64,64,M_DT><<<dim3(128,8),256,0,stream>>>(
      dbcb, dtpjn, 1024, 32, 64, 32, nullptr, dtb, nullptr, nullptr,
      (const float*)d_in[10], nullptr, nullptr);

  // 6. chunked scan
  scan_pass1<<<dim3(NCH,4),256,0,stream>>>(dtb, xcb, dbcb,
      (const float*)d_in[11], flag, chP, chH);
  carry_scan<<<256,64,0,stream>>>(chP, chH, hin);
  scan_pass3<<<dim3(NCH,4),256,0,stream>>>(dtb, xcb, dbcb,
      (const float*)d_in[11], flag, hin, (const float*)d_in[12], zsil, yb);

  // 7. out_proj + feat[order[m]] residual -> x (fp32)  (K=1024)
  gemm_p2<128,128,64,64,M_RES><<<dim3(128,4),256,0,stream>>>(
      yb, outpjn, 512, 1024, 1024, 1024, x, nullptr, nullptr, nullptr,
      (const float*)d_in[0], d_in[1], flag);

  // 8. LN2 -> h2b
  ln2_kernel<<<L_SEQ,256,0,stream>>>(x, (const float*)d_in[14], (const float*)d_in[15], h2b);

  // 9. FFN1 + gelu -> midb  (K=512)
  gemm_p2<128,128,64,64,M_GELU><<<dim3(128,8),256,0,stream>>>(
      h2b, w1tb, 1024, 512, 512, 512, nullptr, midb, nullptr, nullptr,
      (const float*)d_in[17], nullptr, nullptr);

  // 10. FFN2 + bias + residual -> xfin (fp32, serialized order)  (K=1024)
  gemm_p2<128,128,64,64,M_FFN2><<<dim3(128,4),256,0,stream>>>(
      midb, w2tb, 512, 1024, 1024, 1024, xfin, nullptr, nullptr, x,
      (const float*)d_in[19], nullptr, nullptr);

  // 11. out[i] = xfin[inverse[i]]  (fp32)
  final_gather<<<L_SEQ,256,0,stream>>>(xfin, d_in[2], flag, out);
}

// Round 7
// 497.309 us; speedup vs baseline: 1.4728x; 1.0133x over previous
//
#include <hip/hip_runtime.h>

// SerializedMamba on MI355X (gfx950).
// R18: gemm_p2 barrier halving. R17 counters: conflicts 0, FETCH clean,
//      MfmaUtil pinned ~20%, ~50% stall -> the 2-barriers+lgkmcnt(0)-drain
//      per 16-MFMA K-step is the structural cost (m233). With FOUR LDS
//      buffers (64KB; occupancy already 2 blocks/CU) buf[cur] is next
//      overwritten at step st+2, whose stage is issued only after ALL waves
//      passed step st+1's leading barrier -- and arrival there implies each
//      wave's compiler lgkmcnt waits (feeding step-st MFMAs) retired. So the
//      trailing lgkmcnt(0)+s_barrier is provably redundant: ONE barrier per
//      K-step, no LDS drain. vmcnt counts/depth unchanged.
// R17: branch-free softplus (dt_proj 159->~30us).
// R16: 2-way LDS bijection (conflicts 0), depth-2 counted vmcnt, natural
//      block dispatch (no XCD swizzle -- R15 showed it 4x'd FETCH here).
// R13: conv_silu vectorized rolling window; gld_lds width=16 staging.
// R12: scan LC=64/NCH=256, fast-path exp power chain (checkA_k-verified).

#define DEV __device__ __forceinline__

typedef unsigned short u16;
typedef u16    u16x8  __attribute__((ext_vector_type(8)));
typedef __bf16 bf16x8 __attribute__((ext_vector_type(8)));
typedef float  f32x4  __attribute__((ext_vector_type(4)));

static constexpr int L_SEQ = 16384;
static constexpr int LC    = 64;    // scan chunk length
static constexpr int NCH   = 256;   // number of chunks

DEV u16 f2b(float x){
  union { float f; unsigned u; } c; c.f = x;
  unsigned u = c.u;
  return (u16)((u + 0x7fffu + ((u >> 16) & 1u)) >> 16);   // RNE
}
DEV float b2f(u16 h){
  union { unsigned u; float f; } c; c.u = ((unsigned)h) << 16;
  return c.f;
}
DEV int ldix(const void* p, int l, bool is64){
  return is64 ? (int)((const long long*)p)[l] : ((const int*)p)[l];
}
DEV float siluf(float x){ return x / (1.f + __expf(-x)); }
// branch-free: log(1+e^x) = max(x,0) + log(1+e^-|x|); v_exp+v_log intrinsics
DEV float softplusf(float x){
  return fmaxf(x, 0.f) + __logf(1.f + __expf(-fabsf(x)));
}
DEV float geluf(float x){ return 0.5f * x * (1.f + erff(x * 0.70710678118f)); }

// direct global->LDS async copy, 16B per lane (dest must be wave-uniform
// base + lane*16 -- holds for linear tid*16 layouts)
DEV void gld_lds16(const u16* g, u16* l){
  __builtin_amdgcn_global_load_lds(
      (const __attribute__((address_space(1))) unsigned*)g,
      (__attribute__((address_space(3))) unsigned*)l, 16, 0, 0);
}

// r^(s+1) for s=0..15 via log-depth power chain (15 muls after r2/r4/r8)
DEV void pow16(float r, float* a){
  float r2 = r * r, r4 = r2 * r2, r8 = r4 * r4;
  a[0] = r;        a[1] = r2;       a[2] = r2 * r;    a[3] = r4;
  a[4] = r4 * r;   a[5] = r4 * r2;  a[6] = r4 * a[2]; a[7] = r8;
  a[8] = r8 * r;   a[9] = r8 * r2;  a[10] = r8 * a[2]; a[11] = r8 * r4;
  a[12] = r8 * a[4]; a[13] = r8 * a[5]; a[14] = r8 * a[6]; a[15] = r8 * r8;
}

// ---------------------------------------------------------------------------
__global__ __launch_bounds__(256) void fill_k(float* out, float v, unsigned n){
  unsigned i = blockIdx.x * 256 + threadIdx.x;
  if (i < n) out[i] = v;
}

// flag[0]: index inputs are int64. flag[1]: A-structure mismatch (checkA_k).
__global__ void detect_k(const int* ord32, int* flag){
  flag[0] = (ord32[1] == 0 && ord32[3] == 0 && ord32[5] == 0) ? 1 : 0;
  flag[1] = 0;
}

// verify A_log[d][s] == A_log[d][0] + log(s+1)  (=> A[s] = A[0]*(s+1))
__global__ __launch_bounds__(256) void checkA_k(const float* __restrict__ alog,
                                                int* flag){
  int i = blockIdx.x * 256 + threadIdx.x;   // 16384 = d*16+s
  int s = i & 15;
  float v = alog[i];
  float base = alog[i - s];
  if (fabsf(v - (base + __logf((float)(s + 1)))) > 1e-4f) atomicOr(flag + 1, 1);
}

// fp32 -> bf16 pack of the 4 B^T-layout GEMM weights (dense at ws offset 0)
struct NT4 { const float* src[4]; unsigned off[5]; };
__global__ __launch_bounds__(256) void normw_k(NT4 t, u16* dst){
  unsigned i = blockIdx.x * 256 + threadIdx.x;
  if (i >= t.off[4]) return;
  int s = 0;
  #pragma unroll
  for (int k = 1; k <= 3; k++) s += (i >= t.off[k]) ? 1 : 0;
  dst[i] = f2b(t.src[s][i - t.off[s]]);
}

// transpose-convert: out[n*K + k] = f2b(in[k*N + n])
__global__ __launch_bounds__(256) void convT_kernel(const float* __restrict__ in,
                                                    u16* __restrict__ out, int K, int N){
  __shared__ float t[32][33];
  int k0 = blockIdx.x * 32, n0 = blockIdx.y * 32;
  int tx = threadIdx.x & 31, ty = threadIdx.x >> 5;
  #pragma unroll
  for (int i = 0; i < 32; i += 8)
    t[ty + i][tx] = in[(size_t)(k0 + ty + i) * N + n0 + tx];
  __syncthreads();
  #pragma unroll
  for (int i = 0; i < 32; i += 8)
    out[(size_t)(n0 + ty + i) * K + k0 + tx] = f2b(t[tx][ty + i]);
}

// ---------------------------------------------------------------------------
// layernorms (C=512, one block/row, LDS tree)
// ---------------------------------------------------------------------------
__global__ __launch_bounds__(256) void gather_ln1(const float* __restrict__ feat,
    const void* order, const float* __restrict__ w, const float* __restrict__ b,
    const int* flag, u16* __restrict__ x1b){
  __shared__ float rs_[256], rq_[256];
  const bool is64 = flag[0] != 0;
  int l = blockIdx.x, tid = threadIdx.x;
  int src = ldix(order, l, is64);
  float v0 = feat[(size_t)src * 512 + tid];
  float v1 = feat[(size_t)src * 512 + tid + 256];
  rs_[tid] = v0 + v1; rq_[tid] = v0 * v0 + v1 * v1;
  __syncthreads();
  for (int o = 128; o; o >>= 1){
    if (tid < o){ rs_[tid] += rs_[tid + o]; rq_[tid] += rq_[tid + o]; }
    __syncthreads();
  }
  float mu = rs_[0] * (1.f / 512.f);
  float var = rq_[0] * (1.f / 512.f) - mu * mu;
  float rstd = rsqrtf(var + 1e-5f);
  x1b[(size_t)l * 512 + tid]       = f2b((v0 - mu) * rstd * w[tid]       + b[tid]);
  x1b[(size_t)l * 512 + tid + 256] = f2b((v1 - mu) * rstd * w[tid + 256] + b[tid + 256]);
}

__global__ __launch_bounds__(256) void ln2_kernel(const float* __restrict__ x,
    const float* __restrict__ w, const float* __restrict__ b, u16* __restrict__ h2b){
  __shared__ float rs_[256], rq_[256];
  int l = blockIdx.x, tid = threadIdx.x;
  float v0 = x[(size_t)l * 512 + tid];
  float v1 = x[(size_t)l * 512 + tid + 256];
  rs_[tid] = v0 + v1; rq_[tid] = v0 * v0 + v1 * v1;
  __syncthreads();
  for (int o = 128; o; o >>= 1){
    if (tid < o){ rs_[tid] += rs_[tid + o]; rq_[tid] += rq_[tid + o]; }
    __syncthreads();
  }
  float mu = rs_[0] * (1.f / 512.f);
  float var = rq_[0] * (1.f / 512.f) - mu * mu;
  float rstd = rsqrtf(var + 1e-5f);
  h2b[(size_t)l * 512 + tid]       = f2b((v0 - mu) * rstd * w[tid]       + b[tid]);
  h2b[(size_t)l * 512 + tid + 256] = f2b((v1 - mu) * rstd * w[tid + 256] + b[tid + 256]);
}

// ---------------------------------------------------------------------------
// depthwise causal conv (k=4) + silu -- vectorized rolling window.
// ---------------------------------------------------------------------------
__global__ __launch_bounds__(256) void conv_silu(const u16* __restrict__ xm,
    const float* __restrict__ cw, const float* __restrict__ cb, u16* __restrict__ xcb){
  constexpr int TT = 8;
  const int tid = threadIdx.x;
  const int d0 = (tid & 127) * 8;
  const int t0 = (blockIdx.x * 2 + (tid >> 7)) * TT;

  float wk[4][8], bias[8];
  #pragma unroll
  for (int j = 0; j < 8; j++) bias[j] = cb[d0 + j];
  #pragma unroll
  for (int j = 0; j < 8; j++){
    f32x4 v = *(const f32x4*)(cw + (d0 + j) * 4);
    wk[0][j] = v[0]; wk[1][j] = v[1]; wk[2][j] = v[2]; wk[3][j] = v[3];
  }

  float win[3][8];
  #pragma unroll
  for (int k = 0; k < 3; k++){
    int tt = t0 - 3 + k;
    if (tt >= 0){
      u16x8 v = *(const u16x8*)(xm + (size_t)tt * 1024 + d0);
      #pragma unroll
      for (int j = 0; j < 8; j++) win[k][j] = b2f(v[j]);
    } else {
      #pragma unroll
      for (int j = 0; j < 8; j++) win[k][j] = 0.f;
    }
  }

  #pragma unroll
  for (int t = 0; t < TT; t++){
    u16x8 v = *(const u16x8*)(xm + (size_t)(t0 + t) * 1024 + d0);
    u16x8 o;
    float cu[8];
    #pragma unroll
    for (int j = 0; j < 8; j++){
      cu[j] = b2f(v[j]);
      float acc = bias[j] + win[0][j] * wk[0][j] + win[1][j] * wk[1][j]
                + win[2][j] * wk[2][j] + cu[j] * wk[3][j];
      o[j] = f2b(siluf(acc));
    }
    *(u16x8*)(xcb + (size_t)(t0 + t) * 1024 + d0) = o;
    #pragma unroll
    for (int j = 0; j < 8; j++){
      win[0][j] = win[1][j]; win[1][j] = win[2][j]; win[2][j] = cu[j];
    }
  }
}

// ---------------------------------------------------------------------------
// bf16 MFMA GEMM, C = A (MxK, lda) * B^T (NxK, ldb), fused epilogues.
// ---------------------------------------------------------------------------
enum { M_BF16 = 0, M_INPROJ = 1, M_DT = 2, M_RES = 3, M_GELU = 4, M_FFN2 = 5 };

template<int MODE>
DEV void gemm_epilogue(float v, int m, int n, int N,
    float* __restrict__ outf, u16* __restrict__ outb, u16* __restrict__ outb2,
    const float* __restrict__ auxf, const float* __restrict__ auxw,
    const void* ordv, bool is64){
  size_t o = (size_t)m * N + n;
  if constexpr (MODE == M_BF16){
    outb[o] = f2b(v);
  } else if constexpr (MODE == M_INPROJ){
    if (n < 1024) outb [(size_t)m * 1024 + n]          = f2b(v);
    else          outb2[(size_t)m * 1024 + (n - 1024)] = f2b(siluf(v));
  } else if constexpr (MODE == M_DT){
    outb[o] = f2b(softplusf(v + auxw[n]));
  } else if constexpr (MODE == M_RES){
    int src = ldix(ordv, m, is64);
    outf[o] = v + auxw[(size_t)src * 512 + n];   // + feat[order[m]]
  } else if constexpr (MODE == M_GELU){
    outb[o] = f2b(geluf(v + auxw[n]));
  } else { // M_FFN2: + bias + residual -> fp32 (serialized order)
    outf[o] = v + auxw[n] + auxf[o];
  }
}

// R18: depth-2 pipelined GEMM, FOUR LDS buffers, ONE barrier per K-step.
// buf[cur] (read at step st) is next overwritten by the stage issued at step
// st+2, which any wave issues only after passing step st+1's leading barrier;
// arrival there implies all waves' lgkmcnt waits feeding step-st MFMAs have
// retired -> no trailing barrier/drain needed. Counted vmcnt never 0 mid-loop.
// LDS bijection: row's chunk qc lives at slot sub = (qc + (row>>1)) & 3
// (2-way bank aliasing = free); stage source uses inverse, read the forward
// map (involution both-sides, rule #21). Requires K % 32 == 0.
template<int BM, int BN, int WM, int WN, int MODE>
__global__ __launch_bounds__(256) void gemm_p2(
    const u16* __restrict__ A, const u16* __restrict__ B,
    int N, int K, int lda, int ldb,
    float* __restrict__ outf, u16* __restrict__ outb, u16* __restrict__ outb2,
    const float* __restrict__ auxf, const float* __restrict__ auxw,
    const void* ordv, const int* flag){
  constexpr int BK = 32;
  constexpr int MI = WM / 16, NI = WN / 16;
  constexpr int WCOLS = BN / WN;
  constexpr int NA = BM * BK / (256 * 8);
  constexpr int NB = BN * BK / (256 * 8);
  constexpr int LPS = NA + NB;               // gld_lds per thread per stage
  static_assert(LPS == 2 || LPS == 4, "vmcnt literals assume LPS in {2,4}");
  __shared__ __align__(16) u16 sA[4][BM * BK];
  __shared__ __align__(16) u16 sB[4][BN * BK];
  const int tid  = threadIdx.x;
  const int wave = tid >> 6, lane = tid & 63;
  const int wr = wave / WCOLS, wc = wave % WCOLS;
  const int m0 = blockIdx.x * BM, n0 = blockIdx.y * BN;   // natural dispatch
  const int rr = lane & 15;          // fragment row within 16
  const int qc = lane >> 4;          // k-chunk 0..3

  f32x4 acc[MI][NI] = {};

  auto stage = [&](int buf, int k0){
    #pragma unroll
    for (int i = 0; i < NA; i++){
      int idx = tid + i * 256;
      int row = idx >> 2, sub = idx & 3;
      int cg = (sub - (row >> 1)) & 3;
      gld_lds16(A + (size_t)(m0 + row) * lda + k0 + cg * 8, &sA[buf][idx * 8]);
    }
    #pragma unroll
    for (int i = 0; i < NB; i++){
      int idx = tid + i * 256;
      int row = idx >> 2, sub = idx & 3;
      int cg = (sub - (row >> 1)) & 3;
      gld_lds16(B + (size_t)(n0 + row) * ldb + k0 + cg * 8, &sB[buf][idx * 8]);
    }
  };

  const int nst = K / BK;
  stage(0, 0);
  if (nst > 1) stage(1, BK);
  for (int st = 0; st < nst; st++){
    if (st + 2 < nst) stage((st + 2) & 3, (st + 2) * BK);
    // wait for MY stage(st): newer stages in flight = nf, each LPS loads
    const int nf = (st + 2 < nst) ? 2 : ((st + 1 < nst) ? 1 : 0);
    if (nf == 2){
      if constexpr (LPS == 4) asm volatile("s_waitcnt vmcnt(8)" ::: "memory");
      else                    asm volatile("s_waitcnt vmcnt(4)" ::: "memory");
    } else if (nf == 1){
      if constexpr (LPS == 4) asm volatile("s_waitcnt vmcnt(4)" ::: "memory");
      else                    asm volatile("s_waitcnt vmcnt(2)" ::: "memory");
    } else {
      asm volatile("s_waitcnt vmcnt(0)" ::: "memory");
    }
    __builtin_amdgcn_s_barrier();        // everyone's stage(st) landed;
    __builtin_amdgcn_sched_barrier(0);   // also fences reads of st-1 (see hdr)

    const int cur = st & 3;
    bf16x8 af[MI], bfr[NI];
    #pragma unroll
    for (int i = 0; i < MI; i++){
      int R = wr * WM + i * 16 + rr;
      int slot = (qc + (R >> 1)) & 3;
      af[i] = *(const bf16x8*)(&sA[cur][R * BK + slot * 8]);
    }
    #pragma unroll
    for (int j = 0; j < NI; j++){
      int R = wc * WN + j * 16 + rr;
      int slot = (qc + (R >> 1)) & 3;
      bfr[j] = *(const bf16x8*)(&sB[cur][R * BK + slot * 8]);
    }
    #pragma unroll
    for (int i = 0; i < MI; i++)
      #pragma unroll
      for (int j = 0; j < NI; j++)
        acc[i][j] = __builtin_amdgcn_mfma_f32_16x16x32_bf16(af[i], bfr[j], acc[i][j], 0, 0, 0);
    // no trailing barrier: 4-buffer rotation + next iters' leading barriers
    // provide the read-before-overwrite ordering (see kernel header comment)
  }

  const bool is64 = flag ? (flag[0] != 0) : false;
  // D layout: col(N) = lane&15, row(M) = (lane>>4)*4 + r   [m89-verified]
  #pragma unroll
  for (int i = 0; i < MI; i++)
    #pragma unroll
    for (int j = 0; j < NI; j++)
      #pragma unroll
      for (int r = 0; r < 4; r++){
        int m = m0 + wr * WM + i * 16 + ((lane >> 4) << 2) + r;
        int n = n0 + wc * WN + j * 16 + (lane & 15);
        gemm_epilogue<MODE>(acc[i][j][r], m, n, N, outf, outb, outb2,
                            auxf, auxw, ordv, is64);
      }
}

// Legacy BK=32 single-buffer variant (kept for dt_proj, K=32: single step).
template<int BM, int BN, int WM, int WN, int MODE>
__global__ __launch_bounds__(256) void gemm_bt(
    const u16* __restrict__ A, const u16* __restrict__ B,
    int N, int K, int lda, int ldb,
    float* __restrict__ outf, u16* __restrict__ outb, u16* __restrict__ outb2,
    const float* __restrict__ auxf, const float* __restrict__ auxw,
    const void* ordv, const int* flag){
  constexpr int BK = 32;
  constexpr int MI = WM / 16, NI = WN / 16;
  constexpr int WCOLS = BN / WN;
  constexpr int NA = BM * 4 / 256;
  constexpr int NB = BN * 4 / 256;
  __shared__ __align__(16) u16 sA[BM * BK];
  __shared__ __align__(16) u16 sB[BN * BK];
  const int tid  = threadIdx.x;
  const int wave = tid >> 6, lane = tid & 63;
  const int wr = wave / WCOLS, wc = wave % WCOLS;
  const int m0 = blockIdx.x * BM, n0 = blockIdx.y * BN;
  const int rr = lane & 15;
  const int qk = (lane >> 4) * 8;

  f32x4 acc[MI][NI] = {};

  for (int k0 = 0; k0 < K; k0 += BK){
    #pragma unroll
    for (int i = 0; i < NA; i++){
      int idx = tid + i * 256;
      int r = idx >> 2, c = (idx & 3) * 8;
      gld_lds16(A + (size_t)(m0 + r) * lda + k0 + c, sA + (size_t)idx * 8);
    }
    #pragma unroll
    for (int i = 0; i < NB; i++){
      int idx = tid + i * 256;
      int r = idx >> 2, c = (idx & 3) * 8;
      gld_lds16(B + (size_t)(n0 + r) * ldb + k0 + c, sB + (size_t)idx * 8);
    }
    __syncthreads();

    bf16x8 af[MI], bfr[NI];
    #pragma unroll
    for (int i = 0; i < MI; i++)
      af[i] = *(const bf16x8*)(sA + (wr * WM + i * 16 + rr) * BK + qk);
    #pragma unroll
    for (int j = 0; j < NI; j++)
      bfr[j] = *(const bf16x8*)(sB + (wc * WN + j * 16 + rr) * BK + qk);
    #pragma unroll
    for (int i = 0; i < MI; i++)
      #pragma unroll
      for (int j = 0; j < NI; j++)
        acc[i][j] = __builtin_amdgcn_mfma_f32_16x16x32_bf16(af[i], bfr[j], acc[i][j], 0, 0, 0);
    __syncthreads();
  }

  const bool is64 = flag ? (flag[0] != 0) : false;
  #pragma unroll
  for (int i = 0; i < MI; i++)
    #pragma unroll
    for (int j = 0; j < NI; j++)
      #pragma unroll
      for (int r = 0; r < 4; r++){
        int m = m0 + wr * WM + i * 16 + ((lane >> 4) << 2) + r;
        int n = n0 + wc * WN + j * 16 + (lane & 15);
        gemm_epilogue<MODE>(acc[i][j][r], m, n, N, outf, outb, outb2,
                            auxf, auxw, ordv, is64);
      }
}

// ---------------------------------------------------------------------------
// chunked selective scan (fp32 state; chP/chH bf16, layout [chunk][s][d])
// ---------------------------------------------------------------------------
__global__ __launch_bounds__(256) void scan_pass1(const u16* __restrict__ dt,
    const u16* __restrict__ xc, const u16* __restrict__ dbc,
    const float* __restrict__ alog, const int* __restrict__ flag,
    u16* __restrict__ chP, u16* __restrict__ chH){
  __shared__ float sB[LC * 16];
  const int chunk = blockIdx.x;
  const int d = blockIdx.y * 256 + threadIdx.x;
  const int t0 = chunk * LC;
  for (int i = threadIdx.x; i < LC * 16; i += 256){
    int t = i >> 4, s = i & 15;
    sB[i] = b2f(dbc[(size_t)(t0 + t) * 64 + 32 + s]);
  }
  __syncthreads();
  float h[16];
  #pragma unroll
  for (int s = 0; s < 16; s++) h[s] = 0.f;
  float P[16];
  const bool fastA = (flag[1] == 0);
  if (fastA){
    const float a0 = -__expf(alog[(size_t)d * 16]);
    float R = 1.f;
    for (int t = 0; t < LC; t++){
      float dtv = b2f(dt[(size_t)(t0 + t) * 1024 + d]);
      float xv  = b2f(xc[(size_t)(t0 + t) * 1024 + d]);
      float dtx = dtv * xv;
      float r = __expf(dtv * a0);
      R *= r;
      float a_[16];
      pow16(r, a_);
      #pragma unroll
      for (int s = 0; s < 16; s++)
        h[s] = a_[s] * h[s] + dtx * sB[t * 16 + s];
    }
    pow16(R, P);
  } else {
    float A[16];
    #pragma unroll
    for (int s = 0; s < 16; s++){
      A[s] = -__expf(alog[(size_t)d * 16 + s]);
      P[s] = 1.f;
    }
    for (int t = 0; t < LC; t++){
      float dtv = b2f(dt[(size_t)(t0 + t) * 1024 + d]);
      float xv  = b2f(xc[(size_t)(t0 + t) * 1024 + d]);
      float dtx = dtv * xv;
      #pragma unroll
      for (int s = 0; s < 16; s++){
        float a = __expf(dtv * A[s]);
        P[s] *= a;
        h[s] = a * h[s] + dtx * sB[t * 16 + s];
      }
    }
  }
  #pragma unroll
  for (int s = 0; s < 16; s++){
    chP[((size_t)chunk * 16 + s) * 1024 + d] = f2b(P[s]);   // coalesced over d
    chH[((size_t)chunk * 16 + s) * 1024 + d] = f2b(h[s]);
  }
}

// hin may alias chP: window loads 8 ahead into regs before storing.
__global__ __launch_bounds__(64) void carry_scan(const u16* chP, const u16* chH,
                                                 u16* hin){
  int id = blockIdx.x * 64 + threadIdx.x;   // id = s*1024 + d
  float h = 0.f;
  for (int k = 0; k < NCH; k += 8){
    float P[8], E[8];
    #pragma unroll
    for (int j = 0; j < 8; j++){
      P[j] = b2f(chP[(size_t)(k + j) * 16384 + id]);
      E[j] = b2f(chH[(size_t)(k + j) * 16384 + id]);
    }
    #pragma unroll
    for (int j = 0; j < 8; j++){
      hin[(size_t)(k + j) * 16384 + id] = f2b(h);
      h = P[j] * h + E[j];
    }
  }
}

__global__ __launch_bounds__(256) void scan_pass3(const u16* __restrict__ dt,
    const u16* xc, const u16* __restrict__ dbc,
    const float* __restrict__ alog, const int* __restrict__ flag,
    const u16* __restrict__ hin,
    const float* __restrict__ dskip, const u16* __restrict__ zsil, u16* yb){
  __shared__ float sBC[LC * 32];
  const int chunk = blockIdx.x;
  const int d = blockIdx.y * 256 + threadIdx.x;
  const int t0 = chunk * LC;
  for (int i = threadIdx.x; i < LC * 32; i += 256){
    int t = i >> 5, c = i & 31;
    sBC[i] = b2f(dbc[(size_t)(t0 + t) * 64 + 32 + c]);
  }
  __syncthreads();
  float h[16];
  #pragma unroll
  for (int s = 0; s < 16; s++)
    h[s] = b2f(hin[((size_t)chunk * 16 + s) * 1024 + d]);
  const float Dv = dskip[d];
  const bool fastA = (flag[1] == 0);
  if (fastA){
    const float a0 = -__expf(alog[(size_t)d * 16]);
    for (int t = 0; t < LC; t++){
      float dtv = b2f(dt[(size_t)(t0 + t) * 1024 + d]);
      float xv  = b2f(xc[(size_t)(t0 + t) * 1024 + d]);
      float dtx = dtv * xv;
      float r = __expf(dtv * a0);
      float a_[16];
      pow16(r, a_);
      float y = 0.f;
      #pragma unroll
      for (int s = 0; s < 16; s++){
        h[s] = a_[s] * h[s] + dtx * sBC[t * 32 + s];
        y += h[s] * sBC[t * 32 + 16 + s];
      }
      float rv = (y + xv * Dv) * b2f(zsil[(size_t)(t0 + t) * 1024 + d]);
      yb[(size_t)(t0 + t) * 1024 + d] = f2b(rv);
    }
  } else {
    float A[16];
    #pragma unroll
    for (int s = 0; s < 16; s++) A[s] = -__expf(alog[(size_t)d * 16 + s]);
    for (int t = 0; t < LC; t++){
      float dtv = b2f(dt[(size_t)(t0 + t) * 1024 + d]);
      float xv  = b2f(xc[(size_t)(t0 + t) * 1024 + d]);
      float dtx = dtv * xv;
      float y = 0.f;
      #pragma unroll
      for (int s = 0; s < 16; s++){
        float a = __expf(dtv * A[s]);
        h[s] = a * h[s] + dtx * sBC[t * 32 + s];
        y += h[s] * sBC[t * 32 + 16 + s];
      }
      float rv = (y + xv * Dv) * b2f(zsil[(size_t)(t0 + t) * 1024 + d]);
      yb[(size_t)(t0 + t) * 1024 + d] = f2b(rv);
    }
  }
}

// final: out[i] = xfin[inverse[i]] — fp32, sole d_out writer.
__global__ __launch_bounds__(256) void final_gather(const float* __restrict__ xfin,
    const void* inv, const int* flag, float* __restrict__ out){
  const bool is64 = flag[0] != 0;
  int i = blockIdx.x, tid = threadIdx.x;
  int src = ldix(inv, i, is64);
  out[(size_t)i * 512 + tid]       = xfin[(size_t)src * 512 + tid];
  out[(size_t)i * 512 + tid + 256] = xfin[(size_t)src * 512 + tid + 256];
}

// ---------------------------------------------------------------------------
extern "C" void kernel_launch(void* const* d_in, const int* in_sizes, int n_in,
                              void* d_out, int out_size, void* d_ws, size_t ws_size,
                              hipStream_t stream){
  float* out = (float*)d_out;
  char* w = (char*)d_ws;

  // ws layout (bytes). chP/chH (8MB each) on dead x1b region.
  constexpr size_t OFF_W1T  = 3342336;
  constexpr size_t OFF_W2T  = OFF_W1T + 1048576;
  constexpr size_t OFF_FLAG = OFF_W2T + 1048576;
  constexpr size_t OFF_XMB  = 5439744;               // 32MiB xmb / dtb / x(fp32)
  constexpr size_t OFF_ZSIL = OFF_XMB  + 33554432;   // 32MiB zsil / midb
  constexpr size_t OFF_XCB  = OFF_ZSIL + 33554432;   // 32MiB xcb / yb / xfin(fp32)
  constexpr size_t OFF_X1B  = OFF_XCB  + 33554432;   // 16MiB x1b / h2b / chP+chH
  constexpr size_t OFF_DBC  = OFF_X1B  + 16777216;   //  2MiB
  constexpr size_t OFF_CHP  = OFF_X1B;               //  8MiB (over dead x1b)
  constexpr size_t OFF_CHH  = OFF_X1B  + 8388608;    //  8MiB
  constexpr size_t WS_NEED  = OFF_DBC  + 2097152;

  int code = 0;
  static const int want[20] = {8388608,16384,16384,512,512,1048576,4096,1024,
                               65536,32768,1024,16384,1024,524288,512,512,
                               524288,1024,524288,512};
  if (n_in != 20) code = 1000;
  else {
    for (int i = 0; i < 20 && !code; i++)
      if (in_sizes[i] != want[i]) code = 2000 + i * 50;
    if (!code && out_size != 8388608) code = 3000;
    if (!code && ws_size < WS_NEED)   code = 4000;
  }
  if (code){
    unsigned n = (unsigned)(out_size > 0 ? out_size : 1);
    fill_k<<<(n + 255) / 256, 256, 0, stream>>>(out, (float)code, n);
    return;
  }

  u16*   w1tb = (u16*)(w + OFF_W1T);
  u16*   w2tb = (u16*)(w + OFF_W2T);
  int*   flag = (int*)(w + OFF_FLAG);
  u16*   xmb  = (u16*)(w + OFF_XMB);
  u16*   zsil = (u16*)(w + OFF_ZSIL);
  u16*   xcb  = (u16*)(w + OFF_XCB);
  u16*   x1b  = (u16*)(w + OFF_X1B);
  u16*   dbcb = (u16*)(w + OFF_DBC);
  u16*   chP  = (u16*)(w + OFF_CHP);
  u16*   chH  = (u16*)(w + OFF_CHH);
  float* x    = (float*)(w + OFF_XMB);   // fp32 residual over dead dtb
  float* xfin = (float*)(w + OFF_XCB);   // fp32 final (pre-inverse), over dead yb
  u16* dtb  = xmb;   // xmb dead after conv
  u16* yb   = xcb;   // pass3: read-before-write per element
  u16* midb = zsil;  // zsil dead after pass3
  u16* h2b  = x1b;   // x1b dead after in_proj (and chP/chH dead after pass3)
  u16* hin  = chP;   // carry: read-before-write per window

  // bf16-packed GEMM weights at ws offset 0 (element offsets)
  u16* nb = (u16*)w;
  u16* inpjn  = nb;
  u16* xpjn   = nb + 1048576;
  u16* dtpjn  = nb + 1114112;
  u16* outpjn = nb + 1146880;
  NT4 t;
  t.src[0] = (const float*)d_in[5];  t.src[1] = (const float*)d_in[8];
  t.src[2] = (const float*)d_in[9];  t.src[3] = (const float*)d_in[13];
  t.off[0] = 0; t.off[1] = 1048576; t.off[2] = 1114112; t.off[3] = 1146880; t.off[4] = 1671168;

  detect_k<<<1, 1, 0, stream>>>((const int*)d_in[1], flag);
  checkA_k<<<64, 256, 0, stream>>>((const float*)d_in[11], flag);
  normw_k<<<(1671168 + 255) / 256, 256, 0, stream>>>(t, nb);
  convT_kernel<<<dim3(16, 32), 256, 0, stream>>>((const float*)d_in[16], w1tb, 512, 1024);
  convT_kernel<<<dim3(32, 16), 256, 0, stream>>>((const float*)d_in[18], w2tb, 1024, 512);

  // 1. gather + LN1
  gather_ln1<<<L_SEQ, 256, 0, stream>>>((const float*)d_in[0], d_in[1],
      (const float*)d_in[3], (const float*)d_in[4], flag, x1b);

  // 2. in_proj -> xmb | silu(z)   (K=512, 16 pipelined steps)
  gemm_p2<128,128,64,64,M_INPROJ><<<dim3(128,16),256,0,stream>>>(
      x1b, inpjn, 2048, 512, 512, 512, nullptr, xmb, zsil, nullptr, nullptr, nullptr, nullptr);

  // 3. conv + silu
  conv_silu<<<1024, 256, 0, stream>>>(xmb,
      (const float*)d_in[6], (const float*)d_in[7], xcb);

  // 4. x_proj -> dbcb   (K=1024, 32 pipelined steps)
  gemm_p2<64,64,16,64,M_BF16><<<dim3(256,1),256,0,stream>>>(
      xcb, xpjn, 64, 1024, 1024, 1024, nullptr, dbcb, nullptr, nullptr, nullptr, nullptr, nullptr);

  // 5. dt_proj + softplus -> dtb  (K=32: single step, legacy kernel)
  gemm_bt<128,128,64,64,M_DT><<<dim3(128,8),256,0,stream>>>(
      dbcb, dtpjn, 1024, 32, 64, 32, nullptr, dtb, nullptr, nullptr,
      (const float*)d_in[10], nullptr, nullptr);

  // 6. chunked scan
  scan_pass1<<<dim3(NCH,4),256,0,stream>>>(dtb, xcb, dbcb,
      (const float*)d_in[11], flag, chP, chH);
  carry_scan<<<256,64,0,stream>>>(chP, chH, hin);
  scan_pass3<<<dim3(NCH,4),256,0,stream>>>(dtb, xcb, dbcb,
      (const float*)d_in[11], flag, hin, (const float*)d_in[12], zsil, yb);

  // 7. out_proj + feat[order[m]] residual -> x (fp32)  (K=1024)
  gemm_p2<128,128,64,64,M_RES><<<dim3(128,4),256,0,stream>>>(
      yb, outpjn, 512, 1024, 1024, 1024, x, nullptr, nullptr, nullptr,
      (const float*)d_in[0], d_in[1], flag);

  // 8. LN2 -> h2b
  ln2_kernel<<<L_SEQ,256,0,stream>>>(x, (const float*)d_in[14], (const float*)d_in[15], h2b);

  // 9. FFN1 + gelu -> midb  (K=512)
  gemm_p2<128,128,64,64,M_GELU><<<dim3(128,8),256,0,stream>>>(
      h2b, w1tb, 1024, 512, 512, 512, nullptr, midb, nullptr, nullptr,
      (const float*)d_in[17], nullptr, nullptr);

  // 10. FFN2 + bias + residual -> xfin (fp32, serialized order)  (K=1024)
  gemm_p2<128,128,64,64,M_FFN2><<<dim3(128,4),256,0,stream>>>(
      midb, w2tb, 512, 1024, 1024, 1024, xfin, nullptr, nullptr, x,
      (const float*)d_in[19], nullptr, nullptr);

  // 11. out[i] = xfin[inverse[i]]  (fp32)
  final_gather<<<L_SEQ,256,0,stream>>>(xfin, d_in[2], flag, out);
}

// Round 8
// 492.209 us; speedup vs baseline: 1.4881x; 1.0104x over previous
//
#include <hip/hip_runtime.h>

// SerializedMamba on MI355X (gfx950).
// R19: occupancy-geometry round. R18 post-mortem: 4-buf/1-barrier LOST (74us,
//      occ 20%) -- the 4th buffer cost a resident block; 2-phase tweaks are
//      plateaued at ~20% MfmaUtil. This round: revert to the PROVEN R17
//      3-buffer+trailing-barrier schedule, change tile geometry only
//      (parameter lane): BM=256 x BN=128, 8 waves (512 thr), per-wave work
//      unchanged (64x64). LDS 3x24KB=72KB -> 2 blocks/CU = 16 waves/CU (50%
//      cap vs 37.5%). Co-resident block's waves cover barrier stalls (m114).
//      x_proj keeps 64x64/256thr; dt_proj keeps legacy gemm_bt.
// R17: branch-free softplus. R16: 2-way LDS bijection (conflicts 0), depth-2
//      counted vmcnt, natural dispatch (XCD swizzle hurt FETCH here, R15).
// R13: conv_silu vectorized rolling window; gld_lds width=16 staging.
// R12: scan LC=64/NCH=256, fast-path exp power chain (checkA_k-verified).

#define DEV __device__ __forceinline__

typedef unsigned short u16;
typedef u16    u16x8  __attribute__((ext_vector_type(8)));
typedef __bf16 bf16x8 __attribute__((ext_vector_type(8)));
typedef float  f32x4  __attribute__((ext_vector_type(4)));

static constexpr int L_SEQ = 16384;
static constexpr int LC    = 64;    // scan chunk length
static constexpr int NCH   = 256;   // number of chunks

DEV u16 f2b(float x){
  union { float f; unsigned u; } c; c.f = x;
  unsigned u = c.u;
  return (u16)((u + 0x7fffu + ((u >> 16) & 1u)) >> 16);   // RNE
}
DEV float b2f(u16 h){
  union { unsigned u; float f; } c; c.u = ((unsigned)h) << 16;
  return c.f;
}
DEV int ldix(const void* p, int l, bool is64){
  return is64 ? (int)((const long long*)p)[l] : ((const int*)p)[l];
}
DEV float siluf(float x){ return x / (1.f + __expf(-x)); }
// branch-free: log(1+e^x) = max(x,0) + log(1+e^-|x|); v_exp+v_log intrinsics
DEV float softplusf(float x){
  return fmaxf(x, 0.f) + __logf(1.f + __expf(-fabsf(x)));
}
DEV float geluf(float x){ return 0.5f * x * (1.f + erff(x * 0.70710678118f)); }

// direct global->LDS async copy, 16B per lane (dest must be wave-uniform
// base + lane*16 -- holds for linear tid*16 layouts)
DEV void gld_lds16(const u16* g, u16* l){
  __builtin_amdgcn_global_load_lds(
      (const __attribute__((address_space(1))) unsigned*)g,
      (__attribute__((address_space(3))) unsigned*)l, 16, 0, 0);
}

// r^(s+1) for s=0..15 via log-depth power chain (15 muls after r2/r4/r8)
DEV void pow16(float r, float* a){
  float r2 = r * r, r4 = r2 * r2, r8 = r4 * r4;
  a[0] = r;        a[1] = r2;       a[2] = r2 * r;    a[3] = r4;
  a[4] = r4 * r;   a[5] = r4 * r2;  a[6] = r4 * a[2]; a[7] = r8;
  a[8] = r8 * r;   a[9] = r8 * r2;  a[10] = r8 * a[2]; a[11] = r8 * r4;
  a[12] = r8 * a[4]; a[13] = r8 * a[5]; a[14] = r8 * a[6]; a[15] = r8 * r8;
}

// ---------------------------------------------------------------------------
__global__ __launch_bounds__(256) void fill_k(float* out, float v, unsigned n){
  unsigned i = blockIdx.x * 256 + threadIdx.x;
  if (i < n) out[i] = v;
}

// flag[0]: index inputs are int64. flag[1]: A-structure mismatch (checkA_k).
__global__ void detect_k(const int* ord32, int* flag){
  flag[0] = (ord32[1] == 0 && ord32[3] == 0 && ord32[5] == 0) ? 1 : 0;
  flag[1] = 0;
}

// verify A_log[d][s] == A_log[d][0] + log(s+1)  (=> A[s] = A[0]*(s+1))
__global__ __launch_bounds__(256) void checkA_k(const float* __restrict__ alog,
                                                int* flag){
  int i = blockIdx.x * 256 + threadIdx.x;   // 16384 = d*16+s
  int s = i & 15;
  float v = alog[i];
  float base = alog[i - s];
  if (fabsf(v - (base + __logf((float)(s + 1)))) > 1e-4f) atomicOr(flag + 1, 1);
}

// fp32 -> bf16 pack of the 4 B^T-layout GEMM weights (dense at ws offset 0)
struct NT4 { const float* src[4]; unsigned off[5]; };
__global__ __launch_bounds__(256) void normw_k(NT4 t, u16* dst){
  unsigned i = blockIdx.x * 256 + threadIdx.x;
  if (i >= t.off[4]) return;
  int s = 0;
  #pragma unroll
  for (int k = 1; k <= 3; k++) s += (i >= t.off[k]) ? 1 : 0;
  dst[i] = f2b(t.src[s][i - t.off[s]]);
}

// transpose-convert: out[n*K + k] = f2b(in[k*N + n])
__global__ __launch_bounds__(256) void convT_kernel(const float* __restrict__ in,
                                                    u16* __restrict__ out, int K, int N){
  __shared__ float t[32][33];
  int k0 = blockIdx.x * 32, n0 = blockIdx.y * 32;
  int tx = threadIdx.x & 31, ty = threadIdx.x >> 5;
  #pragma unroll
  for (int i = 0; i < 32; i += 8)
    t[ty + i][tx] = in[(size_t)(k0 + ty + i) * N + n0 + tx];
  __syncthreads();
  #pragma unroll
  for (int i = 0; i < 32; i += 8)
    out[(size_t)(n0 + ty + i) * K + k0 + tx] = f2b(t[tx][ty + i]);
}

// ---------------------------------------------------------------------------
// layernorms (C=512, one block/row, LDS tree)
// ---------------------------------------------------------------------------
__global__ __launch_bounds__(256) void gather_ln1(const float* __restrict__ feat,
    const void* order, const float* __restrict__ w, const float* __restrict__ b,
    const int* flag, u16* __restrict__ x1b){
  __shared__ float rs_[256], rq_[256];
  const bool is64 = flag[0] != 0;
  int l = blockIdx.x, tid = threadIdx.x;
  int src = ldix(order, l, is64);
  float v0 = feat[(size_t)src * 512 + tid];
  float v1 = feat[(size_t)src * 512 + tid + 256];
  rs_[tid] = v0 + v1; rq_[tid] = v0 * v0 + v1 * v1;
  __syncthreads();
  for (int o = 128; o; o >>= 1){
    if (tid < o){ rs_[tid] += rs_[tid + o]; rq_[tid] += rq_[tid + o]; }
    __syncthreads();
  }
  float mu = rs_[0] * (1.f / 512.f);
  float var = rq_[0] * (1.f / 512.f) - mu * mu;
  float rstd = rsqrtf(var + 1e-5f);
  x1b[(size_t)l * 512 + tid]       = f2b((v0 - mu) * rstd * w[tid]       + b[tid]);
  x1b[(size_t)l * 512 + tid + 256] = f2b((v1 - mu) * rstd * w[tid + 256] + b[tid + 256]);
}

__global__ __launch_bounds__(256) void ln2_kernel(const float* __restrict__ x,
    const float* __restrict__ w, const float* __restrict__ b, u16* __restrict__ h2b){
  __shared__ float rs_[256], rq_[256];
  int l = blockIdx.x, tid = threadIdx.x;
  float v0 = x[(size_t)l * 512 + tid];
  float v1 = x[(size_t)l * 512 + tid + 256];
  rs_[tid] = v0 + v1; rq_[tid] = v0 * v0 + v1 * v1;
  __syncthreads();
  for (int o = 128; o; o >>= 1){
    if (tid < o){ rs_[tid] += rs_[tid + o]; rq_[tid] += rq_[tid + o]; }
    __syncthreads();
  }
  float mu = rs_[0] * (1.f / 512.f);
  float var = rq_[0] * (1.f / 512.f) - mu * mu;
  float rstd = rsqrtf(var + 1e-5f);
  h2b[(size_t)l * 512 + tid]       = f2b((v0 - mu) * rstd * w[tid]       + b[tid]);
  h2b[(size_t)l * 512 + tid + 256] = f2b((v1 - mu) * rstd * w[tid + 256] + b[tid + 256]);
}

// ---------------------------------------------------------------------------
// depthwise causal conv (k=4) + silu -- vectorized rolling window.
// ---------------------------------------------------------------------------
__global__ __launch_bounds__(256) void conv_silu(const u16* __restrict__ xm,
    const float* __restrict__ cw, const float* __restrict__ cb, u16* __restrict__ xcb){
  constexpr int TT = 8;
  const int tid = threadIdx.x;
  const int d0 = (tid & 127) * 8;
  const int t0 = (blockIdx.x * 2 + (tid >> 7)) * TT;

  float wk[4][8], bias[8];
  #pragma unroll
  for (int j = 0; j < 8; j++) bias[j] = cb[d0 + j];
  #pragma unroll
  for (int j = 0; j < 8; j++){
    f32x4 v = *(const f32x4*)(cw + (d0 + j) * 4);
    wk[0][j] = v[0]; wk[1][j] = v[1]; wk[2][j] = v[2]; wk[3][j] = v[3];
  }

  float win[3][8];
  #pragma unroll
  for (int k = 0; k < 3; k++){
    int tt = t0 - 3 + k;
    if (tt >= 0){
      u16x8 v = *(const u16x8*)(xm + (size_t)tt * 1024 + d0);
      #pragma unroll
      for (int j = 0; j < 8; j++) win[k][j] = b2f(v[j]);
    } else {
      #pragma unroll
      for (int j = 0; j < 8; j++) win[k][j] = 0.f;
    }
  }

  #pragma unroll
  for (int t = 0; t < TT; t++){
    u16x8 v = *(const u16x8*)(xm + (size_t)(t0 + t) * 1024 + d0);
    u16x8 o;
    float cu[8];
    #pragma unroll
    for (int j = 0; j < 8; j++){
      cu[j] = b2f(v[j]);
      float acc = bias[j] + win[0][j] * wk[0][j] + win[1][j] * wk[1][j]
                + win[2][j] * wk[2][j] + cu[j] * wk[3][j];
      o[j] = f2b(siluf(acc));
    }
    *(u16x8*)(xcb + (size_t)(t0 + t) * 1024 + d0) = o;
    #pragma unroll
    for (int j = 0; j < 8; j++){
      win[0][j] = win[1][j]; win[1][j] = win[2][j]; win[2][j] = cu[j];
    }
  }
}

// ---------------------------------------------------------------------------
// bf16 MFMA GEMM, C = A (MxK, lda) * B^T (NxK, ldb), fused epilogues.
// ---------------------------------------------------------------------------
enum { M_BF16 = 0, M_INPROJ = 1, M_DT = 2, M_RES = 3, M_GELU = 4, M_FFN2 = 5 };

template<int MODE>
DEV void gemm_epilogue(float v, int m, int n, int N,
    float* __restrict__ outf, u16* __restrict__ outb, u16* __restrict__ outb2,
    const float* __restrict__ auxf, const float* __restrict__ auxw,
    const void* ordv, bool is64){
  size_t o = (size_t)m * N + n;
  if constexpr (MODE == M_BF16){
    outb[o] = f2b(v);
  } else if constexpr (MODE == M_INPROJ){
    if (n < 1024) outb [(size_t)m * 1024 + n]          = f2b(v);
    else          outb2[(size_t)m * 1024 + (n - 1024)] = f2b(siluf(v));
  } else if constexpr (MODE == M_DT){
    outb[o] = f2b(softplusf(v + auxw[n]));
  } else if constexpr (MODE == M_RES){
    int src = ldix(ordv, m, is64);
    outf[o] = v + auxw[(size_t)src * 512 + n];   // + feat[order[m]]
  } else if constexpr (MODE == M_GELU){
    outb[o] = f2b(geluf(v + auxw[n]));
  } else { // M_FFN2: + bias + residual -> fp32 (serialized order)
    outf[o] = v + auxw[n] + auxf[o];
  }
}

// R19: depth-2 pipelined GEMM (R17 schedule: 3 LDS buffers, counted vmcnt
// never 0 mid-loop, leading barrier + trailing lgkmcnt(0)+barrier), with
// geometry-parametric THREADS = waves*64. LDS bijection: row's chunk qc at
// slot sub = (qc + (row>>1)) & 3 (2-way bank aliasing = free); stage source
// uses the inverse map, read the forward map (involution, rule #21).
// Requires K % 32 == 0.
template<int BM, int BN, int WM, int WN, int MODE>
__global__ __launch_bounds__((BM / WM) * (BN / WN) * 64) void gemm_p2(
    const u16* __restrict__ A, const u16* __restrict__ B,
    int N, int K, int lda, int ldb,
    float* __restrict__ outf, u16* __restrict__ outb, u16* __restrict__ outb2,
    const float* __restrict__ auxf, const float* __restrict__ auxw,
    const void* ordv, const int* flag){
  constexpr int BK = 32;
  constexpr int MI = WM / 16, NI = WN / 16;
  constexpr int WCOLS = BN / WN;
  constexpr int THREADS = (BM / WM) * (BN / WN) * 64;
  constexpr int NA = BM * BK / (THREADS * 8);
  constexpr int NB = BN * BK / (THREADS * 8);
  constexpr int LPS = NA + NB;               // gld_lds per wave per stage
  static_assert(LPS == 2 || LPS == 3 || LPS == 4, "vmcnt literals");
  __shared__ __align__(16) u16 sA[3][BM * BK];
  __shared__ __align__(16) u16 sB[3][BN * BK];
  const int tid  = threadIdx.x;
  const int wave = tid >> 6, lane = tid & 63;
  const int wr = wave / WCOLS, wc = wave % WCOLS;
  const int m0 = blockIdx.x * BM, n0 = blockIdx.y * BN;   // natural dispatch
  const int rr = lane & 15;          // fragment row within 16
  const int qc = lane >> 4;          // k-chunk 0..3

  f32x4 acc[MI][NI] = {};

  auto stage = [&](int buf, int k0){
    #pragma unroll
    for (int i = 0; i < NA; i++){
      int idx = tid + i * THREADS;
      int row = idx >> 2, sub = idx & 3;
      int cg = (sub - (row >> 1)) & 3;
      gld_lds16(A + (size_t)(m0 + row) * lda + k0 + cg * 8, &sA[buf][idx * 8]);
    }
    #pragma unroll
    for (int i = 0; i < NB; i++){
      int idx = tid + i * THREADS;
      int row = idx >> 2, sub = idx & 3;
      int cg = (sub - (row >> 1)) & 3;
      gld_lds16(B + (size_t)(n0 + row) * ldb + k0 + cg * 8, &sB[buf][idx * 8]);
    }
  };

  const int nst = K / BK;
  stage(0, 0);
  if (nst > 1) stage(1, BK);
  for (int st = 0; st < nst; st++){
    if (st + 2 < nst) stage((st + 2) % 3, (st + 2) * BK);
    // wait for MY stage(st): newer stages in flight = nf, each LPS loads
    const int nf = (st + 2 < nst) ? 2 : ((st + 1 < nst) ? 1 : 0);
    if (nf == 2){
      if constexpr (LPS == 4)      asm volatile("s_waitcnt vmcnt(8)" ::: "memory");
      else if constexpr (LPS == 3) asm volatile("s_waitcnt vmcnt(6)" ::: "memory");
      else                         asm volatile("s_waitcnt vmcnt(4)" ::: "memory");
    } else if (nf == 1){
      if constexpr (LPS == 4)      asm volatile("s_waitcnt vmcnt(4)" ::: "memory");
      else if constexpr (LPS == 3) asm volatile("s_waitcnt vmcnt(3)" ::: "memory");
      else                         asm volatile("s_waitcnt vmcnt(2)" ::: "memory");
    } else {
      asm volatile("s_waitcnt vmcnt(0)" ::: "memory");
    }
    __builtin_amdgcn_s_barrier();        // everyone's stage(st) landed
    __builtin_amdgcn_sched_barrier(0);

    const int cur = st % 3;
    bf16x8 af[MI], bfr[NI];
    #pragma unroll
    for (int i = 0; i < MI; i++){
      int R = wr * WM + i * 16 + rr;
      int slot = (qc + (R >> 1)) & 3;
      af[i] = *(const bf16x8*)(&sA[cur][R * BK + slot * 8]);
    }
    #pragma unroll
    for (int j = 0; j < NI; j++){
      int R = wc * WN + j * 16 + rr;
      int slot = (qc + (R >> 1)) & 3;
      bfr[j] = *(const bf16x8*)(&sB[cur][R * BK + slot * 8]);
    }
    #pragma unroll
    for (int i = 0; i < MI; i++)
      #pragma unroll
      for (int j = 0; j < NI; j++)
        acc[i][j] = __builtin_amdgcn_mfma_f32_16x16x32_bf16(af[i], bfr[j], acc[i][j], 0, 0, 0);

    asm volatile("s_waitcnt lgkmcnt(0)" ::: "memory");
    __builtin_amdgcn_s_barrier();        // all reads of buf[cur] done before
    __builtin_amdgcn_sched_barrier(0);   // a later stage overwrites it
  }

  const bool is64 = flag ? (flag[0] != 0) : false;
  // D layout: col(N) = lane&15, row(M) = (lane>>4)*4 + r   [m89-verified]
  #pragma unroll
  for (int i = 0; i < MI; i++)
    #pragma unroll
    for (int j = 0; j < NI; j++)
      #pragma unroll
      for (int r = 0; r < 4; r++){
        int m = m0 + wr * WM + i * 16 + ((lane >> 4) << 2) + r;
        int n = n0 + wc * WN + j * 16 + (lane & 15);
        gemm_epilogue<MODE>(acc[i][j][r], m, n, N, outf, outb, outb2,
                            auxf, auxw, ordv, is64);
      }
}

// Legacy BK=32 single-buffer variant (kept for dt_proj, K=32: single step).
template<int BM, int BN, int WM, int WN, int MODE>
__global__ __launch_bounds__(256) void gemm_bt(
    const u16* __restrict__ A, const u16* __restrict__ B,
    int N, int K, int lda, int ldb,
    float* __restrict__ outf, u16* __restrict__ outb, u16* __restrict__ outb2,
    const float* __restrict__ auxf, const float* __restrict__ auxw,
    const void* ordv, const int* flag){
  constexpr int BK = 32;
  constexpr int MI = WM / 16, NI = WN / 16;
  constexpr int WCOLS = BN / WN;
  constexpr int NA = BM * 4 / 256;
  constexpr int NB = BN * 4 / 256;
  __shared__ __align__(16) u16 sA[BM * BK];
  __shared__ __align__(16) u16 sB[BN * BK];
  const int tid  = threadIdx.x;
  const int wave = tid >> 6, lane = tid & 63;
  const int wr = wave / WCOLS, wc = wave % WCOLS;
  const int m0 = blockIdx.x * BM, n0 = blockIdx.y * BN;
  const int rr = lane & 15;
  const int qk = (lane >> 4) * 8;

  f32x4 acc[MI][NI] = {};

  for (int k0 = 0; k0 < K; k0 += BK){
    #pragma unroll
    for (int i = 0; i < NA; i++){
      int idx = tid + i * 256;
      int r = idx >> 2, c = (idx & 3) * 8;
      gld_lds16(A + (size_t)(m0 + r) * lda + k0 + c, sA + (size_t)idx * 8);
    }
    #pragma unroll
    for (int i = 0; i < NB; i++){
      int idx = tid + i * 256;
      int r = idx >> 2, c = (idx & 3) * 8;
      gld_lds16(B + (size_t)(n0 + r) * ldb + k0 + c, sB + (size_t)idx * 8);
    }
    __syncthreads();

    bf16x8 af[MI], bfr[NI];
    #pragma unroll
    for (int i = 0; i < MI; i++)
      af[i] = *(const bf16x8*)(sA + (wr * WM + i * 16 + rr) * BK + qk);
    #pragma unroll
    for (int j = 0; j < NI; j++)
      bfr[j] = *(const bf16x8*)(sB + (wc * WN + j * 16 + rr) * BK + qk);
    #pragma unroll
    for (int i = 0; i < MI; i++)
      #pragma unroll
      for (int j = 0; j < NI; j++)
        acc[i][j] = __builtin_amdgcn_mfma_f32_16x16x32_bf16(af[i], bfr[j], acc[i][j], 0, 0, 0);
    __syncthreads();
  }

  const bool is64 = flag ? (flag[0] != 0) : false;
  #pragma unroll
  for (int i = 0; i < MI; i++)
    #pragma unroll
    for (int j = 0; j < NI; j++)
      #pragma unroll
      for (int r = 0; r < 4; r++){
        int m = m0 + wr * WM + i * 16 + ((lane >> 4) << 2) + r;
        int n = n0 + wc * WN + j * 16 + (lane & 15);
        gemm_epilogue<MODE>(acc[i][j][r], m, n, N, outf, outb, outb2,
                            auxf, auxw, ordv, is64);
      }
}

// ---------------------------------------------------------------------------
// chunked selective scan (fp32 state; chP/chH bf16, layout [chunk][s][d])
// ---------------------------------------------------------------------------
__global__ __launch_bounds__(256) void scan_pass1(const u16* __restrict__ dt,
    const u16* __restrict__ xc, const u16* __restrict__ dbc,
    const float* __restrict__ alog, const int* __restrict__ flag,
    u16* __restrict__ chP, u16* __restrict__ chH){
  __shared__ float sB[LC * 16];
  const int chunk = blockIdx.x;
  const int d = blockIdx.y * 256 + threadIdx.x;
  const int t0 = chunk * LC;
  for (int i = threadIdx.x; i < LC * 16; i += 256){
    int t = i >> 4, s = i & 15;
    sB[i] = b2f(dbc[(size_t)(t0 + t) * 64 + 32 + s]);
  }
  __syncthreads();
  float h[16];
  #pragma unroll
  for (int s = 0; s < 16; s++) h[s] = 0.f;
  float P[16];
  const bool fastA = (flag[1] == 0);
  if (fastA){
    const float a0 = -__expf(alog[(size_t)d * 16]);
    float R = 1.f;
    for (int t = 0; t < LC; t++){
      float dtv = b2f(dt[(size_t)(t0 + t) * 1024 + d]);
      float xv  = b2f(xc[(size_t)(t0 + t) * 1024 + d]);
      float dtx = dtv * xv;
      float r = __expf(dtv * a0);
      R *= r;
      float a_[16];
      pow16(r, a_);
      #pragma unroll
      for (int s = 0; s < 16; s++)
        h[s] = a_[s] * h[s] + dtx * sB[t * 16 + s];
    }
    pow16(R, P);
  } else {
    float A[16];
    #pragma unroll
    for (int s = 0; s < 16; s++){
      A[s] = -__expf(alog[(size_t)d * 16 + s]);
      P[s] = 1.f;
    }
    for (int t = 0; t < LC; t++){
      float dtv = b2f(dt[(size_t)(t0 + t) * 1024 + d]);
      float xv  = b2f(xc[(size_t)(t0 + t) * 1024 + d]);
      float dtx = dtv * xv;
      #pragma unroll
      for (int s = 0; s < 16; s++){
        float a = __expf(dtv * A[s]);
        P[s] *= a;
        h[s] = a * h[s] + dtx * sB[t * 16 + s];
      }
    }
  }
  #pragma unroll
  for (int s = 0; s < 16; s++){
    chP[((size_t)chunk * 16 + s) * 1024 + d] = f2b(P[s]);   // coalesced over d
    chH[((size_t)chunk * 16 + s) * 1024 + d] = f2b(h[s]);
  }
}

// hin may alias chP: window loads 8 ahead into regs before storing.
__global__ __launch_bounds__(64) void carry_scan(const u16* chP, const u16* chH,
                                                 u16* hin){
  int id = blockIdx.x * 64 + threadIdx.x;   // id = s*1024 + d
  float h = 0.f;
  for (int k = 0; k < NCH; k += 8){
    float P[8], E[8];
    #pragma unroll
    for (int j = 0; j < 8; j++){
      P[j] = b2f(chP[(size_t)(k + j) * 16384 + id]);
      E[j] = b2f(chH[(size_t)(k + j) * 16384 + id]);
    }
    #pragma unroll
    for (int j = 0; j < 8; j++){
      hin[(size_t)(k + j) * 16384 + id] = f2b(h);
      h = P[j] * h + E[j];
    }
  }
}

__global__ __launch_bounds__(256) void scan_pass3(const u16* __restrict__ dt,
    const u16* xc, const u16* __restrict__ dbc,
    const float* __restrict__ alog, const int* __restrict__ flag,
    const u16* __restrict__ hin,
    const float* __restrict__ dskip, const u16* __restrict__ zsil, u16* yb){
  __shared__ float sBC[LC * 32];
  const int chunk = blockIdx.x;
  const int d = blockIdx.y * 256 + threadIdx.x;
  const int t0 = chunk * LC;
  for (int i = threadIdx.x; i < LC * 32; i += 256){
    int t = i >> 5, c = i & 31;
    sBC[i] = b2f(dbc[(size_t)(t0 + t) * 64 + 32 + c]);
  }
  __syncthreads();
  float h[16];
  #pragma unroll
  for (int s = 0; s < 16; s++)
    h[s] = b2f(hin[((size_t)chunk * 16 + s) * 1024 + d]);
  const float Dv = dskip[d];
  const bool fastA = (flag[1] == 0);
  if (fastA){
    const float a0 = -__expf(alog[(size_t)d * 16]);
    for (int t = 0; t < LC; t++){
      float dtv = b2f(dt[(size_t)(t0 + t) * 1024 + d]);
      float xv  = b2f(xc[(size_t)(t0 + t) * 1024 + d]);
      float dtx = dtv * xv;
      float r = __expf(dtv * a0);
      float a_[16];
      pow16(r, a_);
      float y = 0.f;
      #pragma unroll
      for (int s = 0; s < 16; s++){
        h[s] = a_[s] * h[s] + dtx * sBC[t * 32 + s];
        y += h[s] * sBC[t * 32 + 16 + s];
      }
      float rv = (y + xv * Dv) * b2f(zsil[(size_t)(t0 + t) * 1024 + d]);
      yb[(size_t)(t0 + t) * 1024 + d] = f2b(rv);
    }
  } else {
    float A[16];
    #pragma unroll
    for (int s = 0; s < 16; s++) A[s] = -__expf(alog[(size_t)d * 16 + s]);
    for (int t = 0; t < LC; t++){
      float dtv = b2f(dt[(size_t)(t0 + t) * 1024 + d]);
      float xv  = b2f(xc[(size_t)(t0 + t) * 1024 + d]);
      float dtx = dtv * xv;
      float y = 0.f;
      #pragma unroll
      for (int s = 0; s < 16; s++){
        float a = __expf(dtv * A[s]);
        h[s] = a * h[s] + dtx * sBC[t * 32 + s];
        y += h[s] * sBC[t * 32 + 16 + s];
      }
      float rv = (y + xv * Dv) * b2f(zsil[(size_t)(t0 + t) * 1024 + d]);
      yb[(size_t)(t0 + t) * 1024 + d] = f2b(rv);
    }
  }
}

// final: out[i] = xfin[inverse[i]] — fp32, sole d_out writer.
__global__ __launch_bounds__(256) void final_gather(const float* __restrict__ xfin,
    const void* inv, const int* flag, float* __restrict__ out){
  const bool is64 = flag[0] != 0;
  int i = blockIdx.x, tid = threadIdx.x;
  int src = ldix(inv, i, is64);
  out[(size_t)i * 512 + tid]       = xfin[(size_t)src * 512 + tid];
  out[(size_t)i * 512 + tid + 256] = xfin[(size_t)src * 512 + tid + 256];
}

// ---------------------------------------------------------------------------
extern "C" void kernel_launch(void* const* d_in, const int* in_sizes, int n_in,
                              void* d_out, int out_size, void* d_ws, size_t ws_size,
                              hipStream_t stream){
  float* out = (float*)d_out;
  char* w = (char*)d_ws;

  // ws layout (bytes). chP/chH (8MB each) on dead x1b region.
  constexpr size_t OFF_W1T  = 3342336;
  constexpr size_t OFF_W2T  = OFF_W1T + 1048576;
  constexpr size_t OFF_FLAG = OFF_W2T + 1048576;
  constexpr size_t OFF_XMB  = 5439744;               // 32MiB xmb / dtb / x(fp32)
  constexpr size_t OFF_ZSIL = OFF_XMB  + 33554432;   // 32MiB zsil / midb
  constexpr size_t OFF_XCB  = OFF_ZSIL + 33554432;   // 32MiB xcb / yb / xfin(fp32)
  constexpr size_t OFF_X1B  = OFF_XCB  + 33554432;   // 16MiB x1b / h2b / chP+chH
  constexpr size_t OFF_DBC  = OFF_X1B  + 16777216;   //  2MiB
  constexpr size_t OFF_CHP  = OFF_X1B;               //  8MiB (over dead x1b)
  constexpr size_t OFF_CHH  = OFF_X1B  + 8388608;    //  8MiB
  constexpr size_t WS_NEED  = OFF_DBC  + 2097152;

  int code = 0;
  static const int want[20] = {8388608,16384,16384,512,512,1048576,4096,1024,
                               65536,32768,1024,16384,1024,524288,512,512,
                               524288,1024,524288,512};
  if (n_in != 20) code = 1000;
  else {
    for (int i = 0; i < 20 && !code; i++)
      if (in_sizes[i] != want[i]) code = 2000 + i * 50;
    if (!code && out_size != 8388608) code = 3000;
    if (!code && ws_size < WS_NEED)   code = 4000;
  }
  if (code){
    unsigned n = (unsigned)(out_size > 0 ? out_size : 1);
    fill_k<<<(n + 255) / 256, 256, 0, stream>>>(out, (float)code, n);
    return;
  }

  u16*   w1tb = (u16*)(w + OFF_W1T);
  u16*   w2tb = (u16*)(w + OFF_W2T);
  int*   flag = (int*)(w + OFF_FLAG);
  u16*   xmb  = (u16*)(w + OFF_XMB);
  u16*   zsil = (u16*)(w + OFF_ZSIL);
  u16*   xcb  = (u16*)(w + OFF_XCB);
  u16*   x1b  = (u16*)(w + OFF_X1B);
  u16*   dbcb = (u16*)(w + OFF_DBC);
  u16*   chP  = (u16*)(w + OFF_CHP);
  u16*   chH  = (u16*)(w + OFF_CHH);
  float* x    = (float*)(w + OFF_XMB);   // fp32 residual over dead dtb
  float* xfin = (float*)(w + OFF_XCB);   // fp32 final (pre-inverse), over dead yb
  u16* dtb  = xmb;   // xmb dead after conv
  u16* yb   = xcb;   // pass3: read-before-write per element
  u16* midb = zsil;  // zsil dead after pass3
  u16* h2b  = x1b;   // x1b dead after in_proj (and chP/chH dead after pass3)
  u16* hin  = chP;   // carry: read-before-write per window

  // bf16-packed GEMM weights at ws offset 0 (element offsets)
  u16* nb = (u16*)w;
  u16* inpjn  = nb;
  u16* xpjn   = nb + 1048576;
  u16* dtpjn  = nb + 1114112;
  u16* outpjn = nb + 1146880;
  NT4 t;
  t.src[0] = (const float*)d_in[5];  t.src[1] = (const float*)d_in[8];
  t.src[2] = (const float*)d_in[9];  t.src[3] = (const float*)d_in[13];
  t.off[0] = 0; t.off[1] = 1048576; t.off[2] = 1114112; t.off[3] = 1146880; t.off[4] = 1671168;

  detect_k<<<1, 1, 0, stream>>>((const int*)d_in[1], flag);
  checkA_k<<<64, 256, 0, stream>>>((const float*)d_in[11], flag);
  normw_k<<<(1671168 + 255) / 256, 256, 0, stream>>>(t, nb);
  convT_kernel<<<dim3(16, 32), 256, 0, stream>>>((const float*)d_in[16], w1tb, 512, 1024);
  convT_kernel<<<dim3(32, 16), 256, 0, stream>>>((const float*)d_in[18], w2tb, 1024, 512);

  // 1. gather + LN1
  gather_ln1<<<L_SEQ, 256, 0, stream>>>((const float*)d_in[0], d_in[1],
      (const float*)d_in[3], (const float*)d_in[4], flag, x1b);

  // 2. in_proj -> xmb | silu(z)   (K=512; 256x128 tile, 512 thr, 16 steps)
  gemm_p2<256,128,64,64,M_INPROJ><<<dim3(64,16),512,0,stream>>>(
      x1b, inpjn, 2048, 512, 512, 512, nullptr, xmb, zsil, nullptr, nullptr, nullptr, nullptr);

  // 3. conv + silu
  conv_silu<<<1024, 256, 0, stream>>>(xmb,
      (const float*)d_in[6], (const float*)d_in[7], xcb);

  // 4. x_proj -> dbcb   (K=1024; 64x64 tile, 256 thr)
  gemm_p2<64,64,16,64,M_BF16><<<dim3(256,1),256,0,stream>>>(
      xcb, xpjn, 64, 1024, 1024, 1024, nullptr, dbcb, nullptr, nullptr, nullptr, nullptr, nullptr);

  // 5. dt_proj + softplus -> dtb  (K=32: single step, legacy kernel)
  gemm_bt<128,128,64,64,M_DT><<<dim3(128,8),256,0,stream>>>(
      dbcb, dtpjn, 1024, 32, 64, 32, nullptr, dtb, nullptr, nullptr,
      (const float*)d_in[10], nullptr, nullptr);

  // 6. chunked scan
  scan_pass1<<<dim3(NCH,4),256,0,stream>>>(dtb, xcb, dbcb,
      (const float*)d_in[11], flag, chP, chH);
  carry_scan<<<256,64,0,stream>>>(chP, chH, hin);
  scan_pass3<<<dim3(NCH,4),256,0,stream>>>(dtb, xcb, dbcb,
      (const float*)d_in[11], flag, hin, (const float*)d_in[12], zsil, yb);

  // 7. out_proj + feat[order[m]] residual -> x (fp32)  (K=1024; 256x128)
  gemm_p2<256,128,64,64,M_RES><<<dim3(64,4),512,0,stream>>>(
      yb, outpjn, 512, 1024, 1024, 1024, x, nullptr, nullptr, nullptr,
      (const float*)d_in[0], d_in[1], flag);

  // 8. LN2 -> h2b
  ln2_kernel<<<L_SEQ,256,0,stream>>>(x, (const float*)d_in[14], (const float*)d_in[15], h2b);

  // 9. FFN1 + gelu -> midb  (K=512; 256x128)
  gemm_p2<256,128,64,64,M_GELU><<<dim3(64,8),512,0,stream>>>(
      h2b, w1tb, 1024, 512, 512, 512, nullptr, midb, nullptr, nullptr,
      (const float*)d_in[17], nullptr, nullptr);

  // 10. FFN2 + bias + residual -> xfin (fp32)  (K=1024; 256x128)
  gemm_p2<256,128,64,64,M_FFN2><<<dim3(64,4),512,0,stream>>>(
      midb, w2tb, 512, 1024, 1024, 1024, xfin, nullptr, nullptr, x,
      (const float*)d_in[19], nullptr, nullptr);

  // 11. out[i] = xfin[inverse[i]]  (fp32)
  final_gather<<<L_SEQ,256,0,stream>>>(xfin, d_in[2], flag, out);
}